// Round 4
// baseline (515.555 us; speedup 1.0000x reference)
//
#include <hip/hip_runtime.h>
#include <math.h>

#define D 1024
#define S 8192
#define B 8
#define H 16
#define NROWS (B * S)
#define EPS_LN 1e-5f

typedef _Float16 h2 __attribute__((ext_vector_type(2)));

__device__ __forceinline__ float wred_sum(float v) {
#pragma unroll
  for (int m = 1; m < 64; m <<= 1) v += __shfl_xor(v, m, 64);
  return v;
}
__device__ __forceinline__ float wred_max(float v) {
#pragma unroll
  for (int m = 1; m < 64; m <<= 1) v = fmaxf(v, __shfl_xor(v, m, 64));
  return v;
}
__device__ __forceinline__ h2 pkh(float a, float b) {
#if __has_builtin(__builtin_amdgcn_cvt_pkrtz)
  return __builtin_bit_cast(h2, __builtin_amdgcn_cvt_pkrtz(a, b));
#else
  h2 r; r.x = (_Float16)a; r.y = (_Float16)b; return r;
#endif
}
__device__ __forceinline__ float fdot2(h2 a, h2 b, float c) {
#if __has_builtin(__builtin_amdgcn_fdot2)
  typedef __fp16 fp16v2 __attribute__((ext_vector_type(2)));
  return __builtin_amdgcn_fdot2(__builtin_bit_cast(fp16v2, a),
                                __builtin_bit_cast(fp16v2, b), c, false);
#else
  return c + (float)a.x * (float)b.x + (float)a.y * (float)b.y;
#endif
}
__device__ __forceinline__ h2 bch(unsigned int u) { return __builtin_bit_cast(h2, u); }

// ---------- LN over one 1024-row per block (256 thr) ----------
__global__ void k_ln256(const float* __restrict__ in, const float* __restrict__ g,
                        const float* __restrict__ bb, float* __restrict__ out) {
  const int b = blockIdx.x, t = threadIdx.x;
  float4 v = ((const float4*)(in + (size_t)b * D))[t];
  float s = v.x + v.y + v.z + v.w;
  float s2 = fmaf(v.x, v.x, fmaf(v.y, v.y, fmaf(v.z, v.z, v.w * v.w)));
  __shared__ float red[8];
  float ws = wred_sum(s), ws2 = wred_sum(s2);
  const int lane = t & 63, wv = t >> 6;
  if (!lane) { red[wv] = ws; red[wv + 4] = ws2; }
  __syncthreads();
  ws = red[0] + red[1] + red[2] + red[3];
  ws2 = red[4] + red[5] + red[6] + red[7];
  const float m = ws * (1.f / D);
  const float rs = rsqrtf(ws2 * (1.f / D) - m * m + EPS_LN);
  const float4 gg = ((const float4*)g)[t], bv = ((const float4*)bb)[t];
  float4 o;
  o.x = (v.x - m) * rs * gg.x + bv.x;
  o.y = (v.y - m) * rs * gg.y + bv.y;
  o.z = (v.z - m) * rs * gg.z + bv.z;
  o.w = (v.w - m) * rs * gg.w + bv.w;
  ((float4*)(out + (size_t)b * D))[t] = o;
}

// ---------- q[j] = qn . Wq[j,:] + bq[j] : one wave per j ----------
__global__ void k_qproj(const float* __restrict__ qn, const float* __restrict__ Wq,
                        const float* __restrict__ bq, float* __restrict__ q) {
  const int wv = threadIdx.x >> 6, lane = threadIdx.x & 63;
  const int j = blockIdx.x * 4 + wv;
  const float4* wr = (const float4*)(Wq + (size_t)j * D);
  const float4* qr = (const float4*)qn;
  float acc = 0.f;
#pragma unroll
  for (int k = 0; k < 4; k++) {
    float4 a = qr[lane + 64 * k], w = wr[lane + 64 * k];
    acc = fmaf(a.x, w.x, acc); acc = fmaf(a.y, w.y, acc);
    acc = fmaf(a.z, w.z, acc); acc = fmaf(a.w, w.w, acc);
  }
  acc = wred_sum(acc);
  if (!lane) q[j] = acc + bq[j];
}

// ---------- Uf[h][d] = scale * sum_e q[h*64+e] * Wk[h*64+e][d] (fp32) ----------
__global__ void k_uproj(const float* __restrict__ q, const float* __restrict__ Wk,
                        float* __restrict__ Uf) {
  const int idx = blockIdx.x * 256 + threadIdx.x;
  const int h = idx >> 10, d = idx & (D - 1);
  float acc = 0.f;
#pragma unroll 4
  for (int e = 0; e < 64; e++)
    acc = fmaf(q[h * 64 + e], Wk[(size_t)(h * 64 + e) * D + d], acc);
  Uf[idx] = acc * 0.125f;  // 1/sqrt(64)
}

// ---------- prep0: f16 packs of g1/b1 + 5 weight scalars ----------
__global__ void k_prep0(const float* __restrict__ g, const float* __restrict__ b,
                        h2* __restrict__ g1h, h2* __restrict__ b1h,
                        float* __restrict__ sconst) {
  const int t = threadIdx.x;
  float4 gv = ((const float4*)g)[t], bv = ((const float4*)b)[t];
  g1h[2 * t] = pkh(gv.x, gv.y); g1h[2 * t + 1] = pkh(gv.z, gv.w);
  b1h[2 * t] = pkh(bv.x, bv.y); b1h[2 * t + 1] = pkh(bv.z, bv.w);
  float sg = gv.x + gv.y + gv.z + gv.w;
  float sb = bv.x + bv.y + bv.z + bv.w;
  float sbb = bv.x * bv.x + bv.y * bv.y + bv.z * bv.z + bv.w * bv.w;
  float sgb = gv.x * bv.x + gv.y * bv.y + gv.z * bv.z + gv.w * bv.w;
  float sgg = gv.x * gv.x + gv.y * gv.y + gv.z * gv.z + gv.w * gv.w;
  __shared__ float red[4][5];
  sg = wred_sum(sg); sb = wred_sum(sb); sbb = wred_sum(sbb);
  sgb = wred_sum(sgb); sgg = wred_sum(sgg);
  const int lane = t & 63, wv = t >> 6;
  if (!lane) { red[wv][0] = sg; red[wv][1] = sb; red[wv][2] = sbb; red[wv][3] = sgb; red[wv][4] = sgg; }
  __syncthreads();
  if (t < 5) {
    float a = red[0][t] + red[1][t] + red[2][t] + red[3][t];
    sconst[t] = a;
  }
}

// ---------- prep1: C1h = f16(U*g1*kg) + per-head consts c2..c5 ----------
__global__ void k_prep1(const float* __restrict__ Uf, const float* __restrict__ g1,
                        const float* __restrict__ b1, const float* __restrict__ kg,
                        const float* __restrict__ kb, h2* __restrict__ C1h,
                        float* __restrict__ hc) {
  const int h = blockIdx.x, t = threadIdx.x;
  const float4 u = ((const float4*)(Uf + (size_t)h * D))[t];
  const float4 gv = ((const float4*)g1)[t], bv = ((const float4*)b1)[t];
  const float4 kgv = ((const float4*)kg)[t], kbv = ((const float4*)kb)[t];
  const float e0 = u.x * gv.x * kgv.x, e1 = u.y * gv.y * kgv.y;
  const float e2 = u.z * gv.z * kgv.z, e3 = u.w * gv.w * kgv.w;
  C1h[h * 512 + 2 * t] = pkh(e0, e1);
  C1h[h * 512 + 2 * t + 1] = pkh(e2, e3);
  float p2 = u.x * kgv.x * bv.x + u.y * kgv.y * bv.y + u.z * kgv.z * bv.z + u.w * kgv.w * bv.w;
  float p3 = e0 + e1 + e2 + e3;
  float p4 = u.x * kgv.x + u.y * kgv.y + u.z * kgv.z + u.w * kgv.w;
  float p5 = u.x * kbv.x + u.y * kbv.y + u.z * kbv.z + u.w * kbv.w;
  __shared__ float red[4][4];
  p2 = wred_sum(p2); p3 = wred_sum(p3); p4 = wred_sum(p4); p5 = wred_sum(p5);
  const int lane = t & 63, wv = t >> 6;
  if (!lane) { red[wv][0] = p2; red[wv][1] = p3; red[wv][2] = p4; red[wv][3] = p5; }
  __syncthreads();
  if (t < 4) {
    float a = red[0][t] + red[1][t] + red[2][t] + red[3][t];
    hc[t * 16 + h] = a;
  }
}

// ---------- pass 1 over x: fused LN-LN-scores via affine trick ----------
// 16 lanes per row, 4 rows per wave; f16 dot2 for all sums.
__global__ __launch_bounds__(256, 4) void k_scores(
    const float* __restrict__ x, const h2* __restrict__ C1h,
    const h2* __restrict__ g1h, const h2* __restrict__ b1h,
    const float* __restrict__ hc, const float* __restrict__ sconst,
    float* __restrict__ stats, float* __restrict__ sc) {
  __shared__ __align__(16) h2 sC[16 * 512];  // 32 KB  [h][pair]
  __shared__ __align__(16) h2 sG[512], sB[512];
  {
    const uint4* src = (const uint4*)C1h;
    uint4* dst = (uint4*)sC;
    for (int i = threadIdx.x; i < 2048; i += 256) dst[i] = src[i];
    if (threadIdx.x < 128) {
      ((uint4*)sG)[threadIdx.x] = ((const uint4*)g1h)[threadIdx.x];
      ((uint4*)sB)[threadIdx.x] = ((const uint4*)b1h)[threadIdx.x];
    }
  }
  __syncthreads();
  const int lane = threadIdx.x & 63, wv = threadIdx.x >> 6;
  const int g = lane >> 4, j = lane & 15;
  const float c2 = hc[j], c3 = hc[16 + j], c4 = hc[32 + j], c5 = hc[48 + j];
  const float Sg1 = sconst[0], Sb1 = sconst[1], Sbb = sconst[2];
  const float Sgb = sconst[3], Sgg = sconst[4];
  const h2 one = {(_Float16)1.f, (_Float16)1.f};
  const int wid = blockIdx.x * 4 + wv;
#pragma unroll 1
  for (int i = 0; i < 4; i++) {
    const int r = wid * 16 + i * 4 + g;
    const float* xr = x + (size_t)r * D + 8 * j;  // lane cols: 8j..8j+7 per 128-chunk
    h2 xh[32];
    float S0 = 0, S1 = 0, Sa = 0, Sb = 0, Sc = 0, Sd = 0;
#pragma unroll
    for (int c = 0; c < 8; c++) {
      const float4 a = *(const float4*)(xr + 128 * c);
      const float4 b = *(const float4*)(xr + 128 * c + 4);
      const h2 p0 = pkh(a.x, a.y), p1 = pkh(a.z, a.w);
      const h2 p2 = pkh(b.x, b.y), p3 = pkh(b.z, b.w);
      xh[4 * c] = p0; xh[4 * c + 1] = p1; xh[4 * c + 2] = p2; xh[4 * c + 3] = p3;
      const uint4 gu = ((const uint4*)sG)[16 * c + j];
      const uint4 bu = ((const uint4*)sB)[16 * c + j];
      const h2 g0 = bch(gu.x), g1p = bch(gu.y), g2 = bch(gu.z), g3 = bch(gu.w);
      const h2 b0 = bch(bu.x), b1p = bch(bu.y), b2 = bch(bu.z), b3 = bch(bu.w);
      S0 = fdot2(p0, one, S0); S0 = fdot2(p1, one, S0);
      S0 = fdot2(p2, one, S0); S0 = fdot2(p3, one, S0);
      S1 = fdot2(p0, p0, S1); S1 = fdot2(p1, p1, S1);
      S1 = fdot2(p2, p2, S1); S1 = fdot2(p3, p3, S1);
      Sa = fdot2(g0, p0, Sa); Sa = fdot2(g1p, p1, Sa);
      Sa = fdot2(g2, p2, Sa); Sa = fdot2(g3, p3, Sa);
      const h2 gx0 = g0 * p0, gx1 = g1p * p1, gx2 = g2 * p2, gx3 = g3 * p3;
      Sb = fdot2(g0, gx0, Sb); Sb = fdot2(g1p, gx1, Sb);
      Sb = fdot2(g2, gx2, Sb); Sb = fdot2(g3, gx3, Sb);
      Sc = fdot2(gx0, gx0, Sc); Sc = fdot2(gx1, gx1, Sc);
      Sc = fdot2(gx2, gx2, Sc); Sc = fdot2(gx3, gx3, Sc);
      Sd = fdot2(b0, gx0, Sd); Sd = fdot2(b1p, gx1, Sd);
      Sd = fdot2(b2, gx2, Sd); Sd = fdot2(b3, gx3, Sd);
    }
    // head dots: p[h] = sum over lane's cols of C1[h]*x
    float p[16];
#pragma unroll
    for (int h = 0; h < 16; h++) {
      float acc = 0.f;
#pragma unroll
      for (int c = 0; c < 8; c++) {
        const uint4 u = ((const uint4*)sC)[h * 128 + 16 * c + j];
        acc = fdot2(bch(u.x), xh[4 * c], acc);
        acc = fdot2(bch(u.y), xh[4 * c + 1], acc);
        acc = fdot2(bch(u.z), xh[4 * c + 2], acc);
        acc = fdot2(bch(u.w), xh[4 * c + 3], acc);
      }
      p[h] = acc;
    }
    // stats butterfly within 16-lane group
#pragma unroll
    for (int m = 1; m < 16; m <<= 1) {
      S0 += __shfl_xor(S0, m, 64); S1 += __shfl_xor(S1, m, 64);
      Sa += __shfl_xor(Sa, m, 64); Sb += __shfl_xor(Sb, m, 64);
      Sc += __shfl_xor(Sc, m, 64); Sd += __shfl_xor(Sd, m, 64);
    }
    // transpose-reduce: lane j ends with sum over group of p[j]
    float q8[8];
#pragma unroll
    for (int h = 0; h < 8; h++) {
      const float a = p[2 * h], bb = p[2 * h + 1];
      const float sent = (j & 1) ? a : bb;
      const float keep = (j & 1) ? bb : a;
      q8[h] = keep + __shfl_xor(sent, 1, 64);
    }
    float q4[4];
#pragma unroll
    for (int h = 0; h < 4; h++) {
      const float a = q8[2 * h], bb = q8[2 * h + 1];
      const float sent = (j & 2) ? a : bb;
      const float keep = (j & 2) ? bb : a;
      q4[h] = keep + __shfl_xor(sent, 2, 64);
    }
    float q2[2];
#pragma unroll
    for (int h = 0; h < 2; h++) {
      const float a = q4[2 * h], bb = q4[2 * h + 1];
      const float sent = (j & 4) ? a : bb;
      const float keep = (j & 4) ? bb : a;
      q2[h] = keep + __shfl_xor(sent, 4, 64);
    }
    float q1;
    {
      const float a = q2[0], bb = q2[1];
      const float sent = (j & 8) ? a : bb;
      const float keep = (j & 8) ? bb : a;
      q1 = keep + __shfl_xor(sent, 8, 64);
    }
    // final scalars
    const float m1 = S0 * (1.f / D);
    const float rs1 = rsqrtf(S1 * (1.f / D) - m1 * m1 + EPS_LN);
    const float m2 = (rs1 * (Sa - m1 * Sg1) + Sb1) * (1.f / D);
    const float sxn2 = rs1 * rs1 * Sc + 2.f * rs1 * (Sd - m1 * rs1 * Sb) +
                       (Sbb - 2.f * m1 * rs1 * Sgb + m1 * m1 * rs1 * rs1 * Sgg);
    const float rs2 = rsqrtf(sxn2 * (1.f / D) - m2 * m2 + EPS_LN);
    if (j == 0) ((float4*)stats)[r] = make_float4(m1, rs1, m2, rs2);
    const float rs12 = rs1 * rs2;
    sc[(size_t)r * 16 + j] = rs12 * q1 - rs12 * m1 * c3 + rs2 * (c2 - m2 * c4) + c5;
  }
}

// ---------- softmax stage 1: per-chunk max + sum(exp(v-max)) ----------
__global__ void k_smax1(const float* __restrict__ sc, float* __restrict__ pmax,
                        float* __restrict__ psum) {
  const int blk = blockIdx.x, t = threadIdx.x;
  const int b = blk >> 4, c = blk & 15;
  const int r0 = b * S + c * 512;
  __shared__ float lM[4][16], lS[4][16];
  float mx[16];
#pragma unroll
  for (int h = 0; h < 16; h++) mx[h] = -3.4e38f;
#pragma unroll
  for (int rr = 0; rr < 2; rr++) {
    const float4* row = (const float4*)(sc + (size_t)(r0 + t + 256 * rr) * 16);
    const float4 v0 = row[0], v1 = row[1], v2 = row[2], v3 = row[3];
    mx[0] = fmaxf(mx[0], v0.x); mx[1] = fmaxf(mx[1], v0.y);
    mx[2] = fmaxf(mx[2], v0.z); mx[3] = fmaxf(mx[3], v0.w);
    mx[4] = fmaxf(mx[4], v1.x); mx[5] = fmaxf(mx[5], v1.y);
    mx[6] = fmaxf(mx[6], v1.z); mx[7] = fmaxf(mx[7], v1.w);
    mx[8] = fmaxf(mx[8], v2.x); mx[9] = fmaxf(mx[9], v2.y);
    mx[10] = fmaxf(mx[10], v2.z); mx[11] = fmaxf(mx[11], v2.w);
    mx[12] = fmaxf(mx[12], v3.x); mx[13] = fmaxf(mx[13], v3.y);
    mx[14] = fmaxf(mx[14], v3.z); mx[15] = fmaxf(mx[15], v3.w);
  }
  const int lane = t & 63, wv = t >> 6;
#pragma unroll
  for (int h = 0; h < 16; h++) mx[h] = wred_max(mx[h]);
  if (!lane) {
#pragma unroll
    for (int h = 0; h < 16; h++) lM[wv][h] = mx[h];
  }
  __syncthreads();
  float M[16];
#pragma unroll
  for (int h = 0; h < 16; h++)
    M[h] = fmaxf(fmaxf(lM[0][h], lM[1][h]), fmaxf(lM[2][h], lM[3][h]));
  float sm[16];
#pragma unroll
  for (int h = 0; h < 16; h++) sm[h] = 0.f;
#pragma unroll
  for (int rr = 0; rr < 2; rr++) {
    const float4* row = (const float4*)(sc + (size_t)(r0 + t + 256 * rr) * 16);
    const float4 v0 = row[0], v1 = row[1], v2 = row[2], v3 = row[3];
    sm[0] += __expf(v0.x - M[0]); sm[1] += __expf(v0.y - M[1]);
    sm[2] += __expf(v0.z - M[2]); sm[3] += __expf(v0.w - M[3]);
    sm[4] += __expf(v1.x - M[4]); sm[5] += __expf(v1.y - M[5]);
    sm[6] += __expf(v1.z - M[6]); sm[7] += __expf(v1.w - M[7]);
    sm[8] += __expf(v2.x - M[8]); sm[9] += __expf(v2.y - M[9]);
    sm[10] += __expf(v2.z - M[10]); sm[11] += __expf(v2.w - M[11]);
    sm[12] += __expf(v3.x - M[12]); sm[13] += __expf(v3.y - M[13]);
    sm[14] += __expf(v3.z - M[14]); sm[15] += __expf(v3.w - M[15]);
  }
#pragma unroll
  for (int h = 0; h < 16; h++) sm[h] = wred_sum(sm[h]);
  if (!lane) {
#pragma unroll
    for (int h = 0; h < 16; h++) lS[wv][h] = sm[h];
  }
  __syncthreads();
  if (t < 16) {
    float m = fmaxf(fmaxf(lM[0][t], lM[1][t]), fmaxf(lM[2][t], lM[3][t]));
    float s = lS[0][t] + lS[1][t] + lS[2][t] + lS[3][t];
    pmax[blk * 16 + t] = m;
    psum[blk * 16 + t] = s;
  }
}

// ---------- softmax stage 2: combine 16 chunks per (b,h) ----------
__global__ void k_smax2(const float* __restrict__ pmax, const float* __restrict__ psum,
                        float* __restrict__ gmax, float* __restrict__ ginv) {
  const int t = threadIdx.x;  // 128 = B*H
  const int b = t >> 4, h = t & 15;
  float M = -3.4e38f;
  for (int c = 0; c < 16; c++) M = fmaxf(M, pmax[(b * 16 + c) * 16 + h]);
  float sum = 0.f;
  for (int c = 0; c < 16; c++)
    sum += psum[(b * 16 + c) * 16 + h] * __expf(pmax[(b * 16 + c) * 16 + h] - M);
  gmax[t] = M;
  ginv[t] = 1.f / (sum + 1e-9f);
}

// ---------- softmax stage 3: materialize attn in place ----------
__global__ void k_smax3(float* __restrict__ sc, const float* __restrict__ gmax,
                        const float* __restrict__ ginv) {
  const int r = blockIdx.x * 256 + threadIdx.x;
  const int b = r >> 13;
  float4 M[4], I[4];
#pragma unroll
  for (int k = 0; k < 4; k++) {
    M[k] = ((const float4*)(gmax + b * 16))[k];
    I[k] = ((const float4*)(ginv + b * 16))[k];
  }
  float4* row = (float4*)(sc + (size_t)r * 16);
#pragma unroll
  for (int k = 0; k < 4; k++) {
    float4 v = row[k];
    v.x = fminf(fmaxf(__expf(v.x - M[k].x) * I[k].x, 1e-9f), 1.f);
    v.y = fminf(fmaxf(__expf(v.y - M[k].y) * I[k].y, 1e-9f), 1.f);
    v.z = fminf(fmaxf(__expf(v.z - M[k].z) * I[k].z, 1e-9f), 1.f);
    v.w = fminf(fmaxf(__expf(v.w - M[k].w) * I[k].w, 1e-9f), 1.f);
    row[k] = v;
  }
}

// ---------- pass 2 over x: vn recompute + attn-weighted column accumulate ----------
__global__ __launch_bounds__(512) void k_accv(
    const float* __restrict__ x, const float* __restrict__ stats,
    const float* __restrict__ attn,
    const float* __restrict__ g1, const float* __restrict__ b1,
    const float* __restrict__ vg, const float* __restrict__ vb,
    float* __restrict__ part, int CH, int RPC) {
  const int b = blockIdx.x / CH, ch = blockIdx.x % CH;
  const int c0 = threadIdx.x * 2;
  const float2 gv = *(const float2*)(g1 + c0), bv = *(const float2*)(b1 + c0);
  const float2 vgv = *(const float2*)(vg + c0), vbv = *(const float2*)(vb + c0);
  float acc0[16], acc1[16];
#pragma unroll
  for (int h = 0; h < 16; h++) { acc0[h] = 0.f; acc1[h] = 0.f; }
  const int r0 = b * S + ch * RPC;
  for (int i = 0; i < RPC; i++) {
    const int r = r0 + i;
    const float4 st = ((const float4*)stats)[r];  // m1 rs1 m2 rs2
    const float2 xv = *(const float2*)(x + (size_t)r * D + c0);
    float xn0 = (xv.x - st.x) * st.y * gv.x + bv.x;
    float xn1 = (xv.y - st.x) * st.y * gv.y + bv.y;
    const float v0 = (xn0 - st.z) * st.w * vgv.x + vbv.x;
    const float v1 = (xn1 - st.z) * st.w * vgv.y + vbv.y;
    const float* w = attn + (size_t)r * 16;
#pragma unroll
    for (int h = 0; h < 16; h++) {
      const float wh = w[h];
      acc0[h] = fmaf(wh, v0, acc0[h]);
      acc1[h] = fmaf(wh, v1, acc1[h]);
    }
  }
  float* po = part + (size_t)blockIdx.x * (H * D);
#pragma unroll
  for (int h = 0; h < 16; h++)
    *(float2*)(po + h * D + c0) = make_float2(acc0[h], acc1[h]);
}

// ---------- reduce chunk partials -> wsum[b][h][d] ----------
__global__ void k_redpart(const float* __restrict__ part, float* __restrict__ wsum,
                          int CH) {
  const int b = blockIdx.x >> 4, h = blockIdx.x & 15;
  const int d = threadIdx.x * 4;
  float4 a = make_float4(0.f, 0.f, 0.f, 0.f);
  for (int k = 0; k < CH; k++) {
    const float4 p = *(const float4*)(part + ((size_t)(b * CH + k) * H + h) * D + d);
    a.x += p.x; a.y += p.y; a.z += p.z; a.w += p.w;
  }
  *(float4*)(wsum + ((size_t)b * H + h) * D + d) = a;
}

// ---------- out[b][j] = W[j,:] . src[b, (maybe head-sliced)] + bias[j] ----------
__global__ void k_proj8(const float* __restrict__ src, const float* __restrict__ W,
                        const float* __restrict__ bias, float* __restrict__ out,
                        int bstride, int hstride) {
  const int j = blockIdx.x, lane = threadIdx.x;
  const int h = j >> 6;
  const float4* wr = (const float4*)(W + (size_t)j * D);
  float acc[8];
#pragma unroll
  for (int b = 0; b < 8; b++) acc[b] = 0.f;
#pragma unroll
  for (int k = 0; k < 4; k++) {
    const float4 w4 = wr[lane + 64 * k];
#pragma unroll
    for (int b = 0; b < 8; b++) {
      const float4 s4 =
          ((const float4*)(src + (size_t)b * bstride + (size_t)h * hstride))[lane + 64 * k];
      acc[b] = fmaf(w4.x, s4.x, acc[b]); acc[b] = fmaf(w4.y, s4.y, acc[b]);
      acc[b] = fmaf(w4.z, s4.z, acc[b]); acc[b] = fmaf(w4.w, s4.w, acc[b]);
    }
  }
#pragma unroll
  for (int b = 0; b < 8; b++) acc[b] = wred_sum(acc[b]);
  if (!lane) {
    const float bj = bias[j];
#pragma unroll
    for (int b = 0; b < 8; b++) out[(size_t)b * D + j] = acc[b] + bj;
  }
}

extern "C" void kernel_launch(void* const* d_in, const int* in_sizes, int n_in,
                              void* d_out, int out_size, void* d_ws, size_t ws_size,
                              hipStream_t stream) {
  const float* x = (const float*)d_in[0];
  const float* query = (const float*)d_in[1];
  const float* norm_g = (const float*)d_in[2];
  const float* norm_b = (const float*)d_in[3];
  const float* nq_g = (const float*)d_in[4];
  const float* nq_b = (const float*)d_in[5];
  const float* nk_g = (const float*)d_in[6];
  const float* nk_b = (const float*)d_in[7];
  const float* nv_g = (const float*)d_in[8];
  const float* nv_b = (const float*)d_in[9];
  const float* no_g = (const float*)d_in[10];
  const float* no_b = (const float*)d_in[11];
  const float* Wq = (const float*)d_in[12];
  const float* bq = (const float*)d_in[13];
  const float* Wk = (const float*)d_in[14];
  // d_in[15] = bk: constant per (b,h) in scores -> cancels in softmax
  const float* Wv = (const float*)d_in[16];
  const float* bv = (const float*)d_in[17];
  const float* Wo = (const float*)d_in[18];
  const float* bo = (const float*)d_in[19];

  char* ws = (char*)d_ws;
  float* qn = (float*)(ws + 0);
  float* qv = (float*)(ws + 4096);
  float* Uf = (float*)(ws + 8192);
  h2* C1h = (h2*)(ws + 73728);
  h2* g1h = (h2*)(ws + 106496);
  h2* b1h = (h2*)(ws + 108544);
  float* hc = (float*)(ws + 110592);
  float* sconst = (float*)(ws + 110848);
  float* gmax = (float*)(ws + 110912);
  float* ginv = (float*)(ws + 111424);
  float* pmax = (float*)(ws + 111936);
  float* psum = (float*)(ws + 120128);
  float* stats = (float*)(ws + 128320);
  float* sc = (float*)(ws + 1176896);
  float* wsum = (float*)(ws + 5371200);
  float* av = (float*)(ws + 5895488);
  float* yb = (float*)(ws + 5928256);
  float* part = (float*)(ws + 5961024);

  int CH = 32;
  while (CH > 1 && 5961024ull + (size_t)B * CH * H * D * 4 > ws_size) CH >>= 1;
  const int RPC = S / CH;

  k_ln256<<<1, 256, 0, stream>>>(query, nq_g, nq_b, qn);
  k_qproj<<<256, 256, 0, stream>>>(qn, Wq, bq, qv);
  k_uproj<<<64, 256, 0, stream>>>(qv, Wk, Uf);
  k_prep0<<<1, 256, 0, stream>>>(norm_g, norm_b, g1h, b1h, sconst);
  k_prep1<<<16, 256, 0, stream>>>(Uf, norm_g, norm_b, nk_g, nk_b, C1h, hc);
  k_scores<<<1024, 256, 0, stream>>>(x, C1h, g1h, b1h, hc, sconst, stats, sc);
  k_smax1<<<128, 256, 0, stream>>>(sc, pmax, psum);
  k_smax2<<<1, 128, 0, stream>>>(pmax, psum, gmax, ginv);
  k_smax3<<<256, 256, 0, stream>>>(sc, gmax, ginv);
  k_accv<<<B * CH, 512, 0, stream>>>(x, stats, sc, norm_g, norm_b, nv_g, nv_b, part,
                                     CH, RPC);
  k_redpart<<<128, 256, 0, stream>>>(part, wsum, CH);
  k_proj8<<<1024, 64, 0, stream>>>(wsum, Wv, bv, av, H * D, D);  // V-proj on pooled
  k_proj8<<<1024, 64, 0, stream>>>(av, Wo, bo, yb, D, 0);        // O-proj
  k_ln256<<<8, 256, 0, stream>>>(yb, no_g, no_b, (float*)d_out);
}

// Round 5
// 261.289 us; speedup vs baseline: 1.9731x; 1.9731x over previous
//
#include <hip/hip_runtime.h>
#include <math.h>

#define D 1024
#define S 8192
#define B 8
#define H 16
#define NROWS (B * S)
#define EPS_LN 1e-5f

typedef _Float16 h2 __attribute__((ext_vector_type(2)));

__device__ __forceinline__ float wred_sum(float v) {
#pragma unroll
  for (int m = 1; m < 64; m <<= 1) v += __shfl_xor(v, m, 64);
  return v;
}
__device__ __forceinline__ float wred_max(float v) {
#pragma unroll
  for (int m = 1; m < 64; m <<= 1) v = fmaxf(v, __shfl_xor(v, m, 64));
  return v;
}
__device__ __forceinline__ h2 pkh(float a, float b) {
#if __has_builtin(__builtin_amdgcn_cvt_pkrtz)
  return __builtin_bit_cast(h2, __builtin_amdgcn_cvt_pkrtz(a, b));
#else
  h2 r; r.x = (_Float16)a; r.y = (_Float16)b; return r;
#endif
}
__device__ __forceinline__ float fdot2(h2 a, h2 b, float c) {
#if __has_builtin(__builtin_amdgcn_fdot2)
  typedef __fp16 fp16v2 __attribute__((ext_vector_type(2)));
  return __builtin_amdgcn_fdot2(__builtin_bit_cast(fp16v2, a),
                                __builtin_bit_cast(fp16v2, b), c, false);
#else
  return c + (float)a.x * (float)b.x + (float)a.y * (float)b.y;
#endif
}
__device__ __forceinline__ h2 bch(unsigned int u) { return __builtin_bit_cast(h2, u); }

// ---------- LN over one 1024-row per block (256 thr) ----------
__global__ void k_ln256(const float* __restrict__ in, const float* __restrict__ g,
                        const float* __restrict__ bb, float* __restrict__ out) {
  const int b = blockIdx.x, t = threadIdx.x;
  float4 v = ((const float4*)(in + (size_t)b * D))[t];
  float s = v.x + v.y + v.z + v.w;
  float s2 = fmaf(v.x, v.x, fmaf(v.y, v.y, fmaf(v.z, v.z, v.w * v.w)));
  __shared__ float red[8];
  float ws = wred_sum(s), ws2 = wred_sum(s2);
  const int lane = t & 63, wv = t >> 6;
  if (!lane) { red[wv] = ws; red[wv + 4] = ws2; }
  __syncthreads();
  ws = red[0] + red[1] + red[2] + red[3];
  ws2 = red[4] + red[5] + red[6] + red[7];
  const float m = ws * (1.f / D);
  const float rs = rsqrtf(ws2 * (1.f / D) - m * m + EPS_LN);
  const float4 gg = ((const float4*)g)[t], bv = ((const float4*)bb)[t];
  float4 o;
  o.x = (v.x - m) * rs * gg.x + bv.x;
  o.y = (v.y - m) * rs * gg.y + bv.y;
  o.z = (v.z - m) * rs * gg.z + bv.z;
  o.w = (v.w - m) * rs * gg.w + bv.w;
  ((float4*)(out + (size_t)b * D))[t] = o;
}

// ---------- q[j] = qn . Wq[j,:] + bq[j] : one wave per j ----------
__global__ void k_qproj(const float* __restrict__ qn, const float* __restrict__ Wq,
                        const float* __restrict__ bq, float* __restrict__ q) {
  const int wv = threadIdx.x >> 6, lane = threadIdx.x & 63;
  const int j = blockIdx.x * 4 + wv;
  const float4* wr = (const float4*)(Wq + (size_t)j * D);
  const float4* qr = (const float4*)qn;
  float acc = 0.f;
#pragma unroll
  for (int k = 0; k < 4; k++) {
    float4 a = qr[lane + 64 * k], w = wr[lane + 64 * k];
    acc = fmaf(a.x, w.x, acc); acc = fmaf(a.y, w.y, acc);
    acc = fmaf(a.z, w.z, acc); acc = fmaf(a.w, w.w, acc);
  }
  acc = wred_sum(acc);
  if (!lane) q[j] = acc + bq[j];
}

// ---------- Uf[h][d] = scale * sum_e q[h*64+e] * Wk[h*64+e][d] (fp32) ----------
__global__ void k_uproj(const float* __restrict__ q, const float* __restrict__ Wk,
                        float* __restrict__ Uf) {
  const int idx = blockIdx.x * 256 + threadIdx.x;
  const int h = idx >> 10, d = idx & (D - 1);
  float acc = 0.f;
#pragma unroll 4
  for (int e = 0; e < 64; e++)
    acc = fmaf(q[h * 64 + e], Wk[(size_t)(h * 64 + e) * D + d], acc);
  Uf[idx] = acc * 0.125f;  // 1/sqrt(64)
}

// ---------- prep0: f16 packs of g1/b1 + 5 weight scalars ----------
__global__ void k_prep0(const float* __restrict__ g, const float* __restrict__ b,
                        h2* __restrict__ g1h, h2* __restrict__ b1h,
                        float* __restrict__ sconst) {
  const int t = threadIdx.x;
  float4 gv = ((const float4*)g)[t], bv = ((const float4*)b)[t];
  g1h[2 * t] = pkh(gv.x, gv.y); g1h[2 * t + 1] = pkh(gv.z, gv.w);
  b1h[2 * t] = pkh(bv.x, bv.y); b1h[2 * t + 1] = pkh(bv.z, bv.w);
  float sg = gv.x + gv.y + gv.z + gv.w;
  float sb = bv.x + bv.y + bv.z + bv.w;
  float sbb = bv.x * bv.x + bv.y * bv.y + bv.z * bv.z + bv.w * bv.w;
  float sgb = gv.x * bv.x + gv.y * bv.y + gv.z * bv.z + gv.w * bv.w;
  float sgg = gv.x * gv.x + gv.y * gv.y + gv.z * gv.z + gv.w * gv.w;
  __shared__ float red[4][5];
  sg = wred_sum(sg); sb = wred_sum(sb); sbb = wred_sum(sbb);
  sgb = wred_sum(sgb); sgg = wred_sum(sgg);
  const int lane = t & 63, wv = t >> 6;
  if (!lane) { red[wv][0] = sg; red[wv][1] = sb; red[wv][2] = sbb; red[wv][3] = sgb; red[wv][4] = sgg; }
  __syncthreads();
  if (t < 5) {
    float a = red[0][t] + red[1][t] + red[2][t] + red[3][t];
    sconst[t] = a;
  }
}

// ---------- prep1: C1h = f16(U*g1*kg) + per-head consts c2..c5 ----------
__global__ void k_prep1(const float* __restrict__ Uf, const float* __restrict__ g1,
                        const float* __restrict__ b1, const float* __restrict__ kg,
                        const float* __restrict__ kb, h2* __restrict__ C1h,
                        float* __restrict__ hc) {
  const int h = blockIdx.x, t = threadIdx.x;
  const float4 u = ((const float4*)(Uf + (size_t)h * D))[t];
  const float4 gv = ((const float4*)g1)[t], bv = ((const float4*)b1)[t];
  const float4 kgv = ((const float4*)kg)[t], kbv = ((const float4*)kb)[t];
  const float e0 = u.x * gv.x * kgv.x, e1 = u.y * gv.y * kgv.y;
  const float e2 = u.z * gv.z * kgv.z, e3 = u.w * gv.w * kgv.w;
  C1h[h * 512 + 2 * t] = pkh(e0, e1);
  C1h[h * 512 + 2 * t + 1] = pkh(e2, e3);
  float p2 = u.x * kgv.x * bv.x + u.y * kgv.y * bv.y + u.z * kgv.z * bv.z + u.w * kgv.w * bv.w;
  float p3 = e0 + e1 + e2 + e3;
  float p4 = u.x * kgv.x + u.y * kgv.y + u.z * kgv.z + u.w * kgv.w;
  float p5 = u.x * kbv.x + u.y * kbv.y + u.z * kbv.z + u.w * kbv.w;
  __shared__ float red[4][4];
  p2 = wred_sum(p2); p3 = wred_sum(p3); p4 = wred_sum(p4); p5 = wred_sum(p5);
  const int lane = t & 63, wv = t >> 6;
  if (!lane) { red[wv][0] = p2; red[wv][1] = p3; red[wv][2] = p4; red[wv][3] = p5; }
  __syncthreads();
  if (t < 4) {
    float a = red[0][t] + red[1][t] + red[2][t] + red[3][t];
    hc[t * 16 + h] = a;
  }
}

// ---------- pass 1 over x: fused LN-LN-scores via affine trick ----------
// 16 lanes per row, 4 rows per wave; chunk-streaming (no per-lane x array -> no spills)
__global__ __launch_bounds__(256) void k_scores(
    const float* __restrict__ x, const h2* __restrict__ C1h,
    const h2* __restrict__ g1h, const h2* __restrict__ b1h,
    const float* __restrict__ hc, const float* __restrict__ sconst,
    float* __restrict__ stats, float* __restrict__ sc) {
  __shared__ __align__(16) h2 sC[16 * 512];  // 32 KB  [h][pair]
  __shared__ __align__(16) h2 sG[512], sB[512];
  {
    const uint4* src = (const uint4*)C1h;
    uint4* dst = (uint4*)sC;
    for (int i = threadIdx.x; i < 2048; i += 256) dst[i] = src[i];
    if (threadIdx.x < 128) {
      ((uint4*)sG)[threadIdx.x] = ((const uint4*)g1h)[threadIdx.x];
      ((uint4*)sB)[threadIdx.x] = ((const uint4*)b1h)[threadIdx.x];
    }
  }
  __syncthreads();
  const int lane = threadIdx.x & 63, wv = threadIdx.x >> 6;
  const int g = lane >> 4, j = lane & 15;
  const float c2 = hc[j], c3 = hc[16 + j], c4 = hc[32 + j], c5 = hc[48 + j];
  const float Sg1 = sconst[0], Sb1 = sconst[1], Sbb = sconst[2];
  const float Sgb = sconst[3], Sgg = sconst[4];
  const h2 one = {(_Float16)1.f, (_Float16)1.f};
  const int wid = blockIdx.x * 4 + wv;
#pragma unroll 1
  for (int i = 0; i < 4; i++) {
    const int r = wid * 16 + i * 4 + g;
    const float* xr = x + (size_t)r * D + 8 * j;  // lane cols: 8j..8j+7 per 128-chunk
    float p[16];
#pragma unroll
    for (int h = 0; h < 16; h++) p[h] = 0.f;
    float S0 = 0, S1 = 0, Sa = 0, Sb = 0, Sc = 0, Sd = 0;
#pragma unroll
    for (int c = 0; c < 8; c++) {
      const float4 a = *(const float4*)(xr + 128 * c);
      const float4 b = *(const float4*)(xr + 128 * c + 4);
      const h2 p0 = pkh(a.x, a.y), p1 = pkh(a.z, a.w);
      const h2 p2 = pkh(b.x, b.y), p3 = pkh(b.z, b.w);
      const uint4 gu = ((const uint4*)sG)[16 * c + j];
      const uint4 bu = ((const uint4*)sB)[16 * c + j];
      const h2 g0 = bch(gu.x), g1p = bch(gu.y), g2 = bch(gu.z), g3 = bch(gu.w);
      const h2 b0 = bch(bu.x), b1p = bch(bu.y), b2 = bch(bu.z), b3 = bch(bu.w);
      S0 = fdot2(p0, one, S0); S0 = fdot2(p1, one, S0);
      S0 = fdot2(p2, one, S0); S0 = fdot2(p3, one, S0);
      S1 = fdot2(p0, p0, S1); S1 = fdot2(p1, p1, S1);
      S1 = fdot2(p2, p2, S1); S1 = fdot2(p3, p3, S1);
      Sa = fdot2(g0, p0, Sa); Sa = fdot2(g1p, p1, Sa);
      Sa = fdot2(g2, p2, Sa); Sa = fdot2(g3, p3, Sa);
      const h2 gx0 = g0 * p0, gx1 = g1p * p1, gx2 = g2 * p2, gx3 = g3 * p3;
      Sb = fdot2(g0, gx0, Sb); Sb = fdot2(g1p, gx1, Sb);
      Sb = fdot2(g2, gx2, Sb); Sb = fdot2(g3, gx3, Sb);
      Sc = fdot2(gx0, gx0, Sc); Sc = fdot2(gx1, gx1, Sc);
      Sc = fdot2(gx2, gx2, Sc); Sc = fdot2(gx3, gx3, Sc);
      Sd = fdot2(b0, gx0, Sd); Sd = fdot2(b1p, gx1, Sd);
      Sd = fdot2(b2, gx2, Sd); Sd = fdot2(b3, gx3, Sd);
      // head dots for this chunk (x stays in p0..p3 regs, no array)
#pragma unroll
      for (int h = 0; h < 16; h++) {
        const uint4 u = ((const uint4*)sC)[h * 128 + 16 * c + j];
        float acc = p[h];
        acc = fdot2(bch(u.x), p0, acc);
        acc = fdot2(bch(u.y), p1, acc);
        acc = fdot2(bch(u.z), p2, acc);
        acc = fdot2(bch(u.w), p3, acc);
        p[h] = acc;
      }
    }
    // stats butterfly within 16-lane group
#pragma unroll
    for (int m = 1; m < 16; m <<= 1) {
      S0 += __shfl_xor(S0, m, 64); S1 += __shfl_xor(S1, m, 64);
      Sa += __shfl_xor(Sa, m, 64); Sb += __shfl_xor(Sb, m, 64);
      Sc += __shfl_xor(Sc, m, 64); Sd += __shfl_xor(Sd, m, 64);
    }
    // transpose-reduce: lane j ends with sum over group of p[j]
    float q8[8];
#pragma unroll
    for (int h = 0; h < 8; h++) {
      const float a = p[2 * h], bb = p[2 * h + 1];
      const float sent = (j & 1) ? a : bb;
      const float keep = (j & 1) ? bb : a;
      q8[h] = keep + __shfl_xor(sent, 1, 64);
    }
    float q4[4];
#pragma unroll
    for (int h = 0; h < 4; h++) {
      const float a = q8[2 * h], bb = q8[2 * h + 1];
      const float sent = (j & 2) ? a : bb;
      const float keep = (j & 2) ? bb : a;
      q4[h] = keep + __shfl_xor(sent, 2, 64);
    }
    float q2[2];
#pragma unroll
    for (int h = 0; h < 2; h++) {
      const float a = q4[2 * h], bb = q4[2 * h + 1];
      const float sent = (j & 4) ? a : bb;
      const float keep = (j & 4) ? bb : a;
      q2[h] = keep + __shfl_xor(sent, 4, 64);
    }
    float q1;
    {
      const float a = q2[0], bb = q2[1];
      const float sent = (j & 8) ? a : bb;
      const float keep = (j & 8) ? bb : a;
      q1 = keep + __shfl_xor(sent, 8, 64);
    }
    // final scalars
    const float m1 = S0 * (1.f / D);
    const float rs1 = rsqrtf(S1 * (1.f / D) - m1 * m1 + EPS_LN);
    const float m2 = (rs1 * (Sa - m1 * Sg1) + Sb1) * (1.f / D);
    const float sxn2 = rs1 * rs1 * Sc + 2.f * rs1 * (Sd - m1 * rs1 * Sb) +
                       (Sbb - 2.f * m1 * rs1 * Sgb + m1 * m1 * rs1 * rs1 * Sgg);
    const float rs2 = rsqrtf(sxn2 * (1.f / D) - m2 * m2 + EPS_LN);
    if (j == 0) ((float4*)stats)[r] = make_float4(m1, rs1, m2, rs2);
    const float rs12 = rs1 * rs2;
    sc[(size_t)r * 16 + j] = rs12 * q1 - rs12 * m1 * c3 + rs2 * (c2 - m2 * c4) + c5;
  }
}

// ---------- softmax stage 1: per-chunk max + sum(exp(v-max)) ----------
__global__ void k_smax1(const float* __restrict__ sc, float* __restrict__ pmax,
                        float* __restrict__ psum) {
  const int blk = blockIdx.x, t = threadIdx.x;
  const int b = blk >> 4, c = blk & 15;
  const int r0 = b * S + c * 512;
  __shared__ float lM[4][16], lS[4][16];
  float mx[16];
#pragma unroll
  for (int h = 0; h < 16; h++) mx[h] = -3.4e38f;
#pragma unroll
  for (int rr = 0; rr < 2; rr++) {
    const float4* row = (const float4*)(sc + (size_t)(r0 + t + 256 * rr) * 16);
    const float4 v0 = row[0], v1 = row[1], v2 = row[2], v3 = row[3];
    mx[0] = fmaxf(mx[0], v0.x); mx[1] = fmaxf(mx[1], v0.y);
    mx[2] = fmaxf(mx[2], v0.z); mx[3] = fmaxf(mx[3], v0.w);
    mx[4] = fmaxf(mx[4], v1.x); mx[5] = fmaxf(mx[5], v1.y);
    mx[6] = fmaxf(mx[6], v1.z); mx[7] = fmaxf(mx[7], v1.w);
    mx[8] = fmaxf(mx[8], v2.x); mx[9] = fmaxf(mx[9], v2.y);
    mx[10] = fmaxf(mx[10], v2.z); mx[11] = fmaxf(mx[11], v2.w);
    mx[12] = fmaxf(mx[12], v3.x); mx[13] = fmaxf(mx[13], v3.y);
    mx[14] = fmaxf(mx[14], v3.z); mx[15] = fmaxf(mx[15], v3.w);
  }
  const int lane = t & 63, wv = t >> 6;
#pragma unroll
  for (int h = 0; h < 16; h++) mx[h] = wred_max(mx[h]);
  if (!lane) {
#pragma unroll
    for (int h = 0; h < 16; h++) lM[wv][h] = mx[h];
  }
  __syncthreads();
  float M[16];
#pragma unroll
  for (int h = 0; h < 16; h++)
    M[h] = fmaxf(fmaxf(lM[0][h], lM[1][h]), fmaxf(lM[2][h], lM[3][h]));
  float sm[16];
#pragma unroll
  for (int h = 0; h < 16; h++) sm[h] = 0.f;
#pragma unroll
  for (int rr = 0; rr < 2; rr++) {
    const float4* row = (const float4*)(sc + (size_t)(r0 + t + 256 * rr) * 16);
    const float4 v0 = row[0], v1 = row[1], v2 = row[2], v3 = row[3];
    sm[0] += __expf(v0.x - M[0]); sm[1] += __expf(v0.y - M[1]);
    sm[2] += __expf(v0.z - M[2]); sm[3] += __expf(v0.w - M[3]);
    sm[4] += __expf(v1.x - M[4]); sm[5] += __expf(v1.y - M[5]);
    sm[6] += __expf(v1.z - M[6]); sm[7] += __expf(v1.w - M[7]);
    sm[8] += __expf(v2.x - M[8]); sm[9] += __expf(v2.y - M[9]);
    sm[10] += __expf(v2.z - M[10]); sm[11] += __expf(v2.w - M[11]);
    sm[12] += __expf(v3.x - M[12]); sm[13] += __expf(v3.y - M[13]);
    sm[14] += __expf(v3.z - M[14]); sm[15] += __expf(v3.w - M[15]);
  }
#pragma unroll
  for (int h = 0; h < 16; h++) sm[h] = wred_sum(sm[h]);
  if (!lane) {
#pragma unroll
    for (int h = 0; h < 16; h++) lS[wv][h] = sm[h];
  }
  __syncthreads();
  if (t < 16) {
    float m = fmaxf(fmaxf(lM[0][t], lM[1][t]), fmaxf(lM[2][t], lM[3][t]));
    float s = lS[0][t] + lS[1][t] + lS[2][t] + lS[3][t];
    pmax[blk * 16 + t] = m;
    psum[blk * 16 + t] = s;
  }
}

// ---------- softmax stage 2: combine 16 chunks per (b,h) ----------
__global__ void k_smax2(const float* __restrict__ pmax, const float* __restrict__ psum,
                        float* __restrict__ gmax, float* __restrict__ ginv) {
  const int t = threadIdx.x;  // 128 = B*H
  const int b = t >> 4, h = t & 15;
  float M = -3.4e38f;
  for (int c = 0; c < 16; c++) M = fmaxf(M, pmax[(b * 16 + c) * 16 + h]);
  float sum = 0.f;
  for (int c = 0; c < 16; c++)
    sum += psum[(b * 16 + c) * 16 + h] * __expf(pmax[(b * 16 + c) * 16 + h] - M);
  gmax[t] = M;
  ginv[t] = 1.f / (sum + 1e-9f);
}

// ---------- softmax stage 3: materialize attn in place ----------
__global__ void k_smax3(float* __restrict__ sc, const float* __restrict__ gmax,
                        const float* __restrict__ ginv) {
  const int r = blockIdx.x * 256 + threadIdx.x;
  const int b = r >> 13;
  float4 M[4], I[4];
#pragma unroll
  for (int k = 0; k < 4; k++) {
    M[k] = ((const float4*)(gmax + b * 16))[k];
    I[k] = ((const float4*)(ginv + b * 16))[k];
  }
  float4* row = (float4*)(sc + (size_t)r * 16);
#pragma unroll
  for (int k = 0; k < 4; k++) {
    float4 v = row[k];
    v.x = fminf(fmaxf(__expf(v.x - M[k].x) * I[k].x, 1e-9f), 1.f);
    v.y = fminf(fmaxf(__expf(v.y - M[k].y) * I[k].y, 1e-9f), 1.f);
    v.z = fminf(fmaxf(__expf(v.z - M[k].z) * I[k].z, 1e-9f), 1.f);
    v.w = fminf(fmaxf(__expf(v.w - M[k].w) * I[k].w, 1e-9f), 1.f);
    row[k] = v;
  }
}

// ---------- pass 2 over x: vn recompute + attn-weighted column accumulate ----------
__global__ __launch_bounds__(512) void k_accv(
    const float* __restrict__ x, const float* __restrict__ stats,
    const float* __restrict__ attn,
    const float* __restrict__ g1, const float* __restrict__ b1,
    const float* __restrict__ vg, const float* __restrict__ vb,
    float* __restrict__ part, int CH, int RPC) {
  const int b = blockIdx.x / CH, ch = blockIdx.x % CH;
  const int c0 = threadIdx.x * 2;
  const float2 gv = *(const float2*)(g1 + c0), bv = *(const float2*)(b1 + c0);
  const float2 vgv = *(const float2*)(vg + c0), vbv = *(const float2*)(vb + c0);
  float acc0[16], acc1[16];
#pragma unroll
  for (int h = 0; h < 16; h++) { acc0[h] = 0.f; acc1[h] = 0.f; }
  const int r0 = b * S + ch * RPC;
#pragma unroll 2
  for (int i = 0; i < RPC; i++) {
    const int r = r0 + i;
    const float4 st = ((const float4*)stats)[r];  // m1 rs1 m2 rs2
    const float2 xv = *(const float2*)(x + (size_t)r * D + c0);
    float xn0 = (xv.x - st.x) * st.y * gv.x + bv.x;
    float xn1 = (xv.y - st.x) * st.y * gv.y + bv.y;
    const float v0 = (xn0 - st.z) * st.w * vgv.x + vbv.x;
    const float v1 = (xn1 - st.z) * st.w * vgv.y + vbv.y;
    const float* w = attn + (size_t)r * 16;
#pragma unroll
    for (int h = 0; h < 16; h++) {
      const float wh = w[h];
      acc0[h] = fmaf(wh, v0, acc0[h]);
      acc1[h] = fmaf(wh, v1, acc1[h]);
    }
  }
  float* po = part + (size_t)blockIdx.x * (H * D);
#pragma unroll
  for (int h = 0; h < 16; h++)
    *(float2*)(po + h * D + c0) = make_float2(acc0[h], acc1[h]);
}

// ---------- reduce chunk partials -> wsum[b][h][d] ----------
__global__ void k_redpart(const float* __restrict__ part, float* __restrict__ wsum,
                          int CH) {
  const int b = blockIdx.x >> 4, h = blockIdx.x & 15;
  const int d = threadIdx.x * 4;
  float4 a = make_float4(0.f, 0.f, 0.f, 0.f);
  for (int k = 0; k < CH; k++) {
    const float4 p = *(const float4*)(part + ((size_t)(b * CH + k) * H + h) * D + d);
    a.x += p.x; a.y += p.y; a.z += p.z; a.w += p.w;
  }
  *(float4*)(wsum + ((size_t)b * H + h) * D + d) = a;
}

// ---------- out[b][j] = W[j,:] . src[b, (maybe head-sliced)] + bias[j] ----------
__global__ void k_proj8(const float* __restrict__ src, const float* __restrict__ W,
                        const float* __restrict__ bias, float* __restrict__ out,
                        int bstride, int hstride) {
  const int j = blockIdx.x, lane = threadIdx.x;
  const int h = j >> 6;
  const float4* wr = (const float4*)(W + (size_t)j * D);
  float acc[8];
#pragma unroll
  for (int b = 0; b < 8; b++) acc[b] = 0.f;
#pragma unroll
  for (int k = 0; k < 4; k++) {
    const float4 w4 = wr[lane + 64 * k];
#pragma unroll
    for (int b = 0; b < 8; b++) {
      const float4 s4 =
          ((const float4*)(src + (size_t)b * bstride + (size_t)h * hstride))[lane + 64 * k];
      acc[b] = fmaf(w4.x, s4.x, acc[b]); acc[b] = fmaf(w4.y, s4.y, acc[b]);
      acc[b] = fmaf(w4.z, s4.z, acc[b]); acc[b] = fmaf(w4.w, s4.w, acc[b]);
    }
  }
#pragma unroll
  for (int b = 0; b < 8; b++) acc[b] = wred_sum(acc[b]);
  if (!lane) {
    const float bj = bias[j];
#pragma unroll
    for (int b = 0; b < 8; b++) out[(size_t)b * D + j] = acc[b] + bj;
  }
}

extern "C" void kernel_launch(void* const* d_in, const int* in_sizes, int n_in,
                              void* d_out, int out_size, void* d_ws, size_t ws_size,
                              hipStream_t stream) {
  const float* x = (const float*)d_in[0];
  const float* query = (const float*)d_in[1];
  const float* norm_g = (const float*)d_in[2];
  const float* norm_b = (const float*)d_in[3];
  const float* nq_g = (const float*)d_in[4];
  const float* nq_b = (const float*)d_in[5];
  const float* nk_g = (const float*)d_in[6];
  const float* nk_b = (const float*)d_in[7];
  const float* nv_g = (const float*)d_in[8];
  const float* nv_b = (const float*)d_in[9];
  const float* no_g = (const float*)d_in[10];
  const float* no_b = (const float*)d_in[11];
  const float* Wq = (const float*)d_in[12];
  const float* bq = (const float*)d_in[13];
  const float* Wk = (const float*)d_in[14];
  // d_in[15] = bk: constant per (b,h) in scores -> cancels in softmax
  const float* Wv = (const float*)d_in[16];
  const float* bv = (const float*)d_in[17];
  const float* Wo = (const float*)d_in[18];
  const float* bo = (const float*)d_in[19];

  char* ws = (char*)d_ws;
  float* qn = (float*)(ws + 0);
  float* qv = (float*)(ws + 4096);
  float* Uf = (float*)(ws + 8192);
  h2* C1h = (h2*)(ws + 73728);
  h2* g1h = (h2*)(ws + 106496);
  h2* b1h = (h2*)(ws + 108544);
  float* hc = (float*)(ws + 110592);
  float* sconst = (float*)(ws + 110848);
  float* gmax = (float*)(ws + 110912);
  float* ginv = (float*)(ws + 111424);
  float* pmax = (float*)(ws + 111936);
  float* psum = (float*)(ws + 120128);
  float* stats = (float*)(ws + 128320);
  float* sc = (float*)(ws + 1176896);
  float* wsum = (float*)(ws + 5371200);
  float* av = (float*)(ws + 5895488);
  float* yb = (float*)(ws + 5928256);
  float* part = (float*)(ws + 5961024);

  int CH = 64;
  while (CH > 1 && 5961024ull + (size_t)B * CH * H * D * 4 > ws_size) CH >>= 1;
  const int RPC = S / CH;

  k_ln256<<<1, 256, 0, stream>>>(query, nq_g, nq_b, qn);
  k_qproj<<<256, 256, 0, stream>>>(qn, Wq, bq, qv);
  k_uproj<<<64, 256, 0, stream>>>(qv, Wk, Uf);
  k_prep0<<<1, 256, 0, stream>>>(norm_g, norm_b, g1h, b1h, sconst);
  k_prep1<<<16, 256, 0, stream>>>(Uf, norm_g, norm_b, nk_g, nk_b, C1h, hc);
  k_scores<<<1024, 256, 0, stream>>>(x, C1h, g1h, b1h, hc, sconst, stats, sc);
  k_smax1<<<128, 256, 0, stream>>>(sc, pmax, psum);
  k_smax2<<<1, 128, 0, stream>>>(pmax, psum, gmax, ginv);
  k_smax3<<<256, 256, 0, stream>>>(sc, gmax, ginv);
  k_accv<<<B * CH, 512, 0, stream>>>(x, stats, sc, norm_g, norm_b, nv_g, nv_b, part,
                                     CH, RPC);
  k_redpart<<<128, 256, 0, stream>>>(part, wsum, CH);
  k_proj8<<<1024, 64, 0, stream>>>(wsum, Wv, bv, av, H * D, D);  // V-proj on pooled
  k_proj8<<<1024, 64, 0, stream>>>(av, Wo, bo, yb, D, 0);        // O-proj
  k_ln256<<<8, 256, 0, stream>>>(yb, no_g, no_b, (float*)d_out);
}

// Round 6
// 184.375 us; speedup vs baseline: 2.7962x; 1.4172x over previous
//
#include <hip/hip_runtime.h>
#include <math.h>

#define D 1024
#define S 8192
#define B 8
#define H 16
#define NROWS (B * S)
#define EPS_LN 1e-5f

typedef _Float16 h2 __attribute__((ext_vector_type(2)));

__device__ __forceinline__ float wred_sum(float v) {
#pragma unroll
  for (int m = 1; m < 64; m <<= 1) v += __shfl_xor(v, m, 64);
  return v;
}
__device__ __forceinline__ float wred_max(float v) {
#pragma unroll
  for (int m = 1; m < 64; m <<= 1) v = fmaxf(v, __shfl_xor(v, m, 64));
  return v;
}
__device__ __forceinline__ h2 pkh(float a, float b) {
#if __has_builtin(__builtin_amdgcn_cvt_pkrtz)
  return __builtin_bit_cast(h2, __builtin_amdgcn_cvt_pkrtz(a, b));
#else
  h2 r; r.x = (_Float16)a; r.y = (_Float16)b; return r;
#endif
}
__device__ __forceinline__ float fdot2(h2 a, h2 b, float c) {
#if __has_builtin(__builtin_amdgcn_fdot2)
  typedef __fp16 fp16v2 __attribute__((ext_vector_type(2)));
  return __builtin_amdgcn_fdot2(__builtin_bit_cast(fp16v2, a),
                                __builtin_bit_cast(fp16v2, b), c, false);
#else
  return c + (float)a.x * (float)b.x + (float)a.y * (float)b.y;
#endif
}
__device__ __forceinline__ h2 bch(unsigned int u) { return __builtin_bit_cast(h2, u); }

// ---------- LN over one 1024-row per block (256 thr) ----------
__global__ void k_ln256(const float* __restrict__ in, const float* __restrict__ g,
                        const float* __restrict__ bb, float* __restrict__ out) {
  const int b = blockIdx.x, t = threadIdx.x;
  float4 v = ((const float4*)(in + (size_t)b * D))[t];
  float s = v.x + v.y + v.z + v.w;
  float s2 = fmaf(v.x, v.x, fmaf(v.y, v.y, fmaf(v.z, v.z, v.w * v.w)));
  __shared__ float red[8];
  float ws = wred_sum(s), ws2 = wred_sum(s2);
  const int lane = t & 63, wv = t >> 6;
  if (!lane) { red[wv] = ws; red[wv + 4] = ws2; }
  __syncthreads();
  ws = red[0] + red[1] + red[2] + red[3];
  ws2 = red[4] + red[5] + red[6] + red[7];
  const float m = ws * (1.f / D);
  const float rs = rsqrtf(ws2 * (1.f / D) - m * m + EPS_LN);
  const float4 gg = ((const float4*)g)[t], bv = ((const float4*)bb)[t];
  float4 o;
  o.x = (v.x - m) * rs * gg.x + bv.x;
  o.y = (v.y - m) * rs * gg.y + bv.y;
  o.z = (v.z - m) * rs * gg.z + bv.z;
  o.w = (v.w - m) * rs * gg.w + bv.w;
  ((float4*)(out + (size_t)b * D))[t] = o;
}

// ---------- q[j] = qn . Wq[j,:] + bq[j] : one wave per j ----------
__global__ void k_qproj(const float* __restrict__ qn, const float* __restrict__ Wq,
                        const float* __restrict__ bq, float* __restrict__ q) {
  const int wv = threadIdx.x >> 6, lane = threadIdx.x & 63;
  const int j = blockIdx.x * 4 + wv;
  const float4* wr = (const float4*)(Wq + (size_t)j * D);
  const float4* qr = (const float4*)qn;
  float acc = 0.f;
#pragma unroll
  for (int k = 0; k < 4; k++) {
    float4 a = qr[lane + 64 * k], w = wr[lane + 64 * k];
    acc = fmaf(a.x, w.x, acc); acc = fmaf(a.y, w.y, acc);
    acc = fmaf(a.z, w.z, acc); acc = fmaf(a.w, w.w, acc);
  }
  acc = wred_sum(acc);
  if (!lane) q[j] = acc + bq[j];
}

// ---------- Uf[h][d] = scale * sum_e q[h*64+e] * Wk[h*64+e][d] (fp32) ----------
__global__ void k_uproj(const float* __restrict__ q, const float* __restrict__ Wk,
                        float* __restrict__ Uf) {
  const int idx = blockIdx.x * 256 + threadIdx.x;
  const int h = idx >> 10, d = idx & (D - 1);
  float acc = 0.f;
#pragma unroll 4
  for (int e = 0; e < 64; e++)
    acc = fmaf(q[h * 64 + e], Wk[(size_t)(h * 64 + e) * D + d], acc);
  Uf[idx] = acc * 0.125f;  // 1/sqrt(64)
}

// ---------- prep0: f16 packs of g1/b1 + 5 weight scalars ----------
__global__ void k_prep0(const float* __restrict__ g, const float* __restrict__ b,
                        h2* __restrict__ g1h, h2* __restrict__ b1h,
                        float* __restrict__ sconst) {
  const int t = threadIdx.x;
  float4 gv = ((const float4*)g)[t], bv = ((const float4*)b)[t];
  g1h[2 * t] = pkh(gv.x, gv.y); g1h[2 * t + 1] = pkh(gv.z, gv.w);
  b1h[2 * t] = pkh(bv.x, bv.y); b1h[2 * t + 1] = pkh(bv.z, bv.w);
  float sg = gv.x + gv.y + gv.z + gv.w;
  float sb = bv.x + bv.y + bv.z + bv.w;
  float sbb = bv.x * bv.x + bv.y * bv.y + bv.z * bv.z + bv.w * bv.w;
  float sgb = gv.x * bv.x + gv.y * bv.y + gv.z * bv.z + gv.w * bv.w;
  float sgg = gv.x * gv.x + gv.y * gv.y + gv.z * gv.z + gv.w * gv.w;
  __shared__ float red[4][5];
  sg = wred_sum(sg); sb = wred_sum(sb); sbb = wred_sum(sbb);
  sgb = wred_sum(sgb); sgg = wred_sum(sgg);
  const int lane = t & 63, wv = t >> 6;
  if (!lane) { red[wv][0] = sg; red[wv][1] = sb; red[wv][2] = sbb; red[wv][3] = sgb; red[wv][4] = sgg; }
  __syncthreads();
  if (t < 5) {
    float a = red[0][t] + red[1][t] + red[2][t] + red[3][t];
    sconst[t] = a;
  }
}

// ---------- prep1: C1h = f16(U*g1*kg) + per-head consts c2..c5 ----------
__global__ void k_prep1(const float* __restrict__ Uf, const float* __restrict__ g1,
                        const float* __restrict__ b1, const float* __restrict__ kg,
                        const float* __restrict__ kb, h2* __restrict__ C1h,
                        float* __restrict__ hc) {
  const int h = blockIdx.x, t = threadIdx.x;
  const float4 u = ((const float4*)(Uf + (size_t)h * D))[t];
  const float4 gv = ((const float4*)g1)[t], bv = ((const float4*)b1)[t];
  const float4 kgv = ((const float4*)kg)[t], kbv = ((const float4*)kb)[t];
  const float e0 = u.x * gv.x * kgv.x, e1 = u.y * gv.y * kgv.y;
  const float e2 = u.z * gv.z * kgv.z, e3 = u.w * gv.w * kgv.w;
  C1h[h * 512 + 2 * t] = pkh(e0, e1);
  C1h[h * 512 + 2 * t + 1] = pkh(e2, e3);
  float p2 = u.x * kgv.x * bv.x + u.y * kgv.y * bv.y + u.z * kgv.z * bv.z + u.w * kgv.w * bv.w;
  float p3 = e0 + e1 + e2 + e3;
  float p4 = u.x * kgv.x + u.y * kgv.y + u.z * kgv.z + u.w * kgv.w;
  float p5 = u.x * kbv.x + u.y * kbv.y + u.z * kbv.z + u.w * kbv.w;
  __shared__ float red[4][4];
  p2 = wred_sum(p2); p3 = wred_sum(p3); p4 = wred_sum(p4); p5 = wred_sum(p5);
  const int lane = t & 63, wv = t >> 6;
  if (!lane) { red[wv][0] = p2; red[wv][1] = p3; red[wv][2] = p4; red[wv][3] = p5; }
  __syncthreads();
  if (t < 4) {
    float a = red[0][t] + red[1][t] + red[2][t] + red[3][t];
    hc[t * 16 + h] = a;
  }
}

// ---------- pass 1 over x: fused LN-LN-scores via affine trick ----------
// 16 lanes per row, 4 rows per wave; chunk-streaming; VGPR capped for 3 waves/SIMD
__global__ __launch_bounds__(256, 3) void k_scores(
    const float* __restrict__ x, const h2* __restrict__ C1h,
    const h2* __restrict__ g1h, const h2* __restrict__ b1h,
    const float* __restrict__ hc, const float* __restrict__ sconst,
    float* __restrict__ stats, float* __restrict__ sc) {
  __shared__ __align__(16) h2 sC[16 * 512];  // 32 KB  [h][pair]
  __shared__ __align__(16) h2 sG[512], sB[512];
  {
    const uint4* src = (const uint4*)C1h;
    uint4* dst = (uint4*)sC;
    for (int i = threadIdx.x; i < 2048; i += 256) dst[i] = src[i];
    if (threadIdx.x < 128) {
      ((uint4*)sG)[threadIdx.x] = ((const uint4*)g1h)[threadIdx.x];
      ((uint4*)sB)[threadIdx.x] = ((const uint4*)b1h)[threadIdx.x];
    }
  }
  __syncthreads();
  const int lane = threadIdx.x & 63, wv = threadIdx.x >> 6;
  const int g = lane >> 4, j = lane & 15;
  const float c2 = hc[j], c3 = hc[16 + j], c4 = hc[32 + j], c5 = hc[48 + j];
  const float Sg1 = sconst[0], Sb1 = sconst[1], Sbb = sconst[2];
  const float Sgb = sconst[3], Sgg = sconst[4];
  const h2 one = {(_Float16)1.f, (_Float16)1.f};
  const int wid = blockIdx.x * 4 + wv;
#pragma unroll 1
  for (int i = 0; i < 4; i++) {
    const int r = wid * 16 + i * 4 + g;
    const float* xr = x + (size_t)r * D + 8 * j;  // lane cols: 8j..8j+7 per 128-chunk
    float p[16];
#pragma unroll
    for (int h = 0; h < 16; h++) p[h] = 0.f;
    float S0 = 0, S1 = 0, Sa = 0, Sb = 0, Sc = 0, Sd = 0;
#pragma unroll 4
    for (int c = 0; c < 8; c++) {
      const float4 a = *(const float4*)(xr + 128 * c);
      const float4 b = *(const float4*)(xr + 128 * c + 4);
      const h2 p0 = pkh(a.x, a.y), p1 = pkh(a.z, a.w);
      const h2 p2 = pkh(b.x, b.y), p3 = pkh(b.z, b.w);
      const uint4 gu = ((const uint4*)sG)[16 * c + j];
      const uint4 bu = ((const uint4*)sB)[16 * c + j];
      const h2 g0 = bch(gu.x), g1p = bch(gu.y), g2 = bch(gu.z), g3 = bch(gu.w);
      const h2 b0 = bch(bu.x), b1p = bch(bu.y), b2 = bch(bu.z), b3 = bch(bu.w);
      S0 = fdot2(p0, one, S0); S0 = fdot2(p1, one, S0);
      S0 = fdot2(p2, one, S0); S0 = fdot2(p3, one, S0);
      S1 = fdot2(p0, p0, S1); S1 = fdot2(p1, p1, S1);
      S1 = fdot2(p2, p2, S1); S1 = fdot2(p3, p3, S1);
      Sa = fdot2(g0, p0, Sa); Sa = fdot2(g1p, p1, Sa);
      Sa = fdot2(g2, p2, Sa); Sa = fdot2(g3, p3, Sa);
      const h2 gx0 = g0 * p0, gx1 = g1p * p1, gx2 = g2 * p2, gx3 = g3 * p3;
      Sb = fdot2(g0, gx0, Sb); Sb = fdot2(g1p, gx1, Sb);
      Sb = fdot2(g2, gx2, Sb); Sb = fdot2(g3, gx3, Sb);
      Sc = fdot2(gx0, gx0, Sc); Sc = fdot2(gx1, gx1, Sc);
      Sc = fdot2(gx2, gx2, Sc); Sc = fdot2(gx3, gx3, Sc);
      Sd = fdot2(b0, gx0, Sd); Sd = fdot2(b1p, gx1, Sd);
      Sd = fdot2(b2, gx2, Sd); Sd = fdot2(b3, gx3, Sd);
      // head dots for this chunk (x stays in p0..p3 regs, no array)
#pragma unroll
      for (int h = 0; h < 16; h++) {
        const uint4 u = ((const uint4*)sC)[h * 128 + 16 * c + j];
        float acc = p[h];
        acc = fdot2(bch(u.x), p0, acc);
        acc = fdot2(bch(u.y), p1, acc);
        acc = fdot2(bch(u.z), p2, acc);
        acc = fdot2(bch(u.w), p3, acc);
        p[h] = acc;
      }
    }
    // stats butterfly within 16-lane group
#pragma unroll
    for (int m = 1; m < 16; m <<= 1) {
      S0 += __shfl_xor(S0, m, 64); S1 += __shfl_xor(S1, m, 64);
      Sa += __shfl_xor(Sa, m, 64); Sb += __shfl_xor(Sb, m, 64);
      Sc += __shfl_xor(Sc, m, 64); Sd += __shfl_xor(Sd, m, 64);
    }
    // transpose-reduce: lane j ends with sum over group of p[j]
    float q8[8];
#pragma unroll
    for (int h = 0; h < 8; h++) {
      const float a = p[2 * h], bb = p[2 * h + 1];
      const float sent = (j & 1) ? a : bb;
      const float keep = (j & 1) ? bb : a;
      q8[h] = keep + __shfl_xor(sent, 1, 64);
    }
    float q4[4];
#pragma unroll
    for (int h = 0; h < 4; h++) {
      const float a = q8[2 * h], bb = q8[2 * h + 1];
      const float sent = (j & 2) ? a : bb;
      const float keep = (j & 2) ? bb : a;
      q4[h] = keep + __shfl_xor(sent, 2, 64);
    }
    float q2[2];
#pragma unroll
    for (int h = 0; h < 2; h++) {
      const float a = q4[2 * h], bb = q4[2 * h + 1];
      const float sent = (j & 4) ? a : bb;
      const float keep = (j & 4) ? bb : a;
      q2[h] = keep + __shfl_xor(sent, 4, 64);
    }
    float q1;
    {
      const float a = q2[0], bb = q2[1];
      const float sent = (j & 8) ? a : bb;
      const float keep = (j & 8) ? bb : a;
      q1 = keep + __shfl_xor(sent, 8, 64);
    }
    // final scalars
    const float m1 = S0 * (1.f / D);
    const float rs1 = rsqrtf(S1 * (1.f / D) - m1 * m1 + EPS_LN);
    const float m2 = (rs1 * (Sa - m1 * Sg1) + Sb1) * (1.f / D);
    const float sxn2 = rs1 * rs1 * Sc + 2.f * rs1 * (Sd - m1 * rs1 * Sb) +
                       (Sbb - 2.f * m1 * rs1 * Sgb + m1 * m1 * rs1 * rs1 * Sgg);
    const float rs2 = rsqrtf(sxn2 * (1.f / D) - m2 * m2 + EPS_LN);
    if (j == 0) ((float4*)stats)[r] = make_float4(m1, rs1, m2, rs2);
    const float rs12 = rs1 * rs2;
    sc[(size_t)r * 16 + j] = rs12 * q1 - rs12 * m1 * c3 + rs2 * (c2 - m2 * c4) + c5;
  }
}

// ---------- softmax stage 1: per-chunk max + sum(exp(v-max)) ----------
__global__ void k_smax1(const float* __restrict__ sc, float* __restrict__ pmax,
                        float* __restrict__ psum) {
  const int blk = blockIdx.x, t = threadIdx.x;
  const int b = blk >> 4, c = blk & 15;
  const int r0 = b * S + c * 512;
  __shared__ float lM[4][16], lS[4][16];
  float mx[16];
#pragma unroll
  for (int h = 0; h < 16; h++) mx[h] = -3.4e38f;
#pragma unroll
  for (int rr = 0; rr < 2; rr++) {
    const float4* row = (const float4*)(sc + (size_t)(r0 + t + 256 * rr) * 16);
    const float4 v0 = row[0], v1 = row[1], v2 = row[2], v3 = row[3];
    mx[0] = fmaxf(mx[0], v0.x); mx[1] = fmaxf(mx[1], v0.y);
    mx[2] = fmaxf(mx[2], v0.z); mx[3] = fmaxf(mx[3], v0.w);
    mx[4] = fmaxf(mx[4], v1.x); mx[5] = fmaxf(mx[5], v1.y);
    mx[6] = fmaxf(mx[6], v1.z); mx[7] = fmaxf(mx[7], v1.w);
    mx[8] = fmaxf(mx[8], v2.x); mx[9] = fmaxf(mx[9], v2.y);
    mx[10] = fmaxf(mx[10], v2.z); mx[11] = fmaxf(mx[11], v2.w);
    mx[12] = fmaxf(mx[12], v3.x); mx[13] = fmaxf(mx[13], v3.y);
    mx[14] = fmaxf(mx[14], v3.z); mx[15] = fmaxf(mx[15], v3.w);
  }
  const int lane = t & 63, wv = t >> 6;
#pragma unroll
  for (int h = 0; h < 16; h++) mx[h] = wred_max(mx[h]);
  if (!lane) {
#pragma unroll
    for (int h = 0; h < 16; h++) lM[wv][h] = mx[h];
  }
  __syncthreads();
  float M[16];
#pragma unroll
  for (int h = 0; h < 16; h++)
    M[h] = fmaxf(fmaxf(lM[0][h], lM[1][h]), fmaxf(lM[2][h], lM[3][h]));
  float sm[16];
#pragma unroll
  for (int h = 0; h < 16; h++) sm[h] = 0.f;
#pragma unroll
  for (int rr = 0; rr < 2; rr++) {
    const float4* row = (const float4*)(sc + (size_t)(r0 + t + 256 * rr) * 16);
    const float4 v0 = row[0], v1 = row[1], v2 = row[2], v3 = row[3];
    sm[0] += __expf(v0.x - M[0]); sm[1] += __expf(v0.y - M[1]);
    sm[2] += __expf(v0.z - M[2]); sm[3] += __expf(v0.w - M[3]);
    sm[4] += __expf(v1.x - M[4]); sm[5] += __expf(v1.y - M[5]);
    sm[6] += __expf(v1.z - M[6]); sm[7] += __expf(v1.w - M[7]);
    sm[8] += __expf(v2.x - M[8]); sm[9] += __expf(v2.y - M[9]);
    sm[10] += __expf(v2.z - M[10]); sm[11] += __expf(v2.w - M[11]);
    sm[12] += __expf(v3.x - M[12]); sm[13] += __expf(v3.y - M[13]);
    sm[14] += __expf(v3.z - M[14]); sm[15] += __expf(v3.w - M[15]);
  }
#pragma unroll
  for (int h = 0; h < 16; h++) sm[h] = wred_sum(sm[h]);
  if (!lane) {
#pragma unroll
    for (int h = 0; h < 16; h++) lS[wv][h] = sm[h];
  }
  __syncthreads();
  if (t < 16) {
    float m = fmaxf(fmaxf(lM[0][t], lM[1][t]), fmaxf(lM[2][t], lM[3][t]));
    float s = lS[0][t] + lS[1][t] + lS[2][t] + lS[3][t];
    pmax[blk * 16 + t] = m;
    psum[blk * 16 + t] = s;
  }
}

// ---------- softmax stage 2: combine 16 chunks per (b,h) ----------
__global__ void k_smax2(const float* __restrict__ pmax, const float* __restrict__ psum,
                        float* __restrict__ gmax, float* __restrict__ ginv) {
  const int t = threadIdx.x;  // 128 = B*H
  const int b = t >> 4, h = t & 15;
  float M = -3.4e38f;
  for (int c = 0; c < 16; c++) M = fmaxf(M, pmax[(b * 16 + c) * 16 + h]);
  float sum = 0.f;
  for (int c = 0; c < 16; c++)
    sum += psum[(b * 16 + c) * 16 + h] * __expf(pmax[(b * 16 + c) * 16 + h] - M);
  gmax[t] = M;
  ginv[t] = 1.f / (sum + 1e-9f);
}

// ---------- softmax stage 3: materialize attn in place ----------
__global__ void k_smax3(float* __restrict__ sc, const float* __restrict__ gmax,
                        const float* __restrict__ ginv) {
  const int r = blockIdx.x * 256 + threadIdx.x;
  const int b = r >> 13;
  float4 M[4], I[4];
#pragma unroll
  for (int k = 0; k < 4; k++) {
    M[k] = ((const float4*)(gmax + b * 16))[k];
    I[k] = ((const float4*)(ginv + b * 16))[k];
  }
  float4* row = (float4*)(sc + (size_t)r * 16);
#pragma unroll
  for (int k = 0; k < 4; k++) {
    float4 v = row[k];
    v.x = fminf(fmaxf(__expf(v.x - M[k].x) * I[k].x, 1e-9f), 1.f);
    v.y = fminf(fmaxf(__expf(v.y - M[k].y) * I[k].y, 1e-9f), 1.f);
    v.z = fminf(fmaxf(__expf(v.z - M[k].z) * I[k].z, 1e-9f), 1.f);
    v.w = fminf(fmaxf(__expf(v.w - M[k].w) * I[k].w, 1e-9f), 1.f);
    row[k] = v;
  }
}

// ---------- pass 2 over x: vn recompute + attn-weighted column accumulate ----------
__global__ __launch_bounds__(512) void k_accv(
    const float* __restrict__ x, const float* __restrict__ stats,
    const float* __restrict__ attn,
    const float* __restrict__ g1, const float* __restrict__ b1,
    const float* __restrict__ vg, const float* __restrict__ vb,
    float* __restrict__ part, int CH, int RPC) {
  const int b = blockIdx.x / CH, ch = blockIdx.x % CH;
  const int c0 = threadIdx.x * 2;
  const float2 gv = *(const float2*)(g1 + c0), bv = *(const float2*)(b1 + c0);
  const float2 vgv = *(const float2*)(vg + c0), vbv = *(const float2*)(vb + c0);
  float acc0[16], acc1[16];
#pragma unroll
  for (int h = 0; h < 16; h++) { acc0[h] = 0.f; acc1[h] = 0.f; }
  const int r0 = b * S + ch * RPC;
#pragma unroll 2
  for (int i = 0; i < RPC; i++) {
    const int r = r0 + i;
    const float4 st = ((const float4*)stats)[r];  // m1 rs1 m2 rs2
    const float2 xv = *(const float2*)(x + (size_t)r * D + c0);
    float xn0 = (xv.x - st.x) * st.y * gv.x + bv.x;
    float xn1 = (xv.y - st.x) * st.y * gv.y + bv.y;
    const float v0 = (xn0 - st.z) * st.w * vgv.x + vbv.x;
    const float v1 = (xn1 - st.z) * st.w * vgv.y + vbv.y;
    const float* w = attn + (size_t)r * 16;
#pragma unroll
    for (int h = 0; h < 16; h++) {
      const float wh = w[h];
      acc0[h] = fmaf(wh, v0, acc0[h]);
      acc1[h] = fmaf(wh, v1, acc1[h]);
    }
  }
  float* po = part + (size_t)blockIdx.x * (H * D);
#pragma unroll
  for (int h = 0; h < 16; h++)
    *(float2*)(po + h * D + c0) = make_float2(acc0[h], acc1[h]);
}

// ---------- reduce chunk partials -> wsum[b][h][d] ----------
__global__ void k_redpart(const float* __restrict__ part, float* __restrict__ wsum,
                          int CH) {
  const int b = blockIdx.x >> 4, h = blockIdx.x & 15;
  const int d = threadIdx.x * 4;
  float4 a = make_float4(0.f, 0.f, 0.f, 0.f);
  for (int k = 0; k < CH; k++) {
    const float4 p = *(const float4*)(part + ((size_t)(b * CH + k) * H + h) * D + d);
    a.x += p.x; a.y += p.y; a.z += p.z; a.w += p.w;
  }
  *(float4*)(wsum + ((size_t)b * H + h) * D + d) = a;
}

// ---------- out[b][j] = W[j,:] . src[b, (maybe head-sliced)] + bias[j] ----------
__global__ void k_proj8(const float* __restrict__ src, const float* __restrict__ W,
                        const float* __restrict__ bias, float* __restrict__ out,
                        int bstride, int hstride) {
  const int j = blockIdx.x, lane = threadIdx.x;
  const int h = j >> 6;
  const float4* wr = (const float4*)(W + (size_t)j * D);
  float acc[8];
#pragma unroll
  for (int b = 0; b < 8; b++) acc[b] = 0.f;
#pragma unroll
  for (int k = 0; k < 4; k++) {
    const float4 w4 = wr[lane + 64 * k];
#pragma unroll
    for (int b = 0; b < 8; b++) {
      const float4 s4 =
          ((const float4*)(src + (size_t)b * bstride + (size_t)h * hstride))[lane + 64 * k];
      acc[b] = fmaf(w4.x, s4.x, acc[b]); acc[b] = fmaf(w4.y, s4.y, acc[b]);
      acc[b] = fmaf(w4.z, s4.z, acc[b]); acc[b] = fmaf(w4.w, s4.w, acc[b]);
    }
  }
#pragma unroll
  for (int b = 0; b < 8; b++) acc[b] = wred_sum(acc[b]);
  if (!lane) {
    const float bj = bias[j];
#pragma unroll
    for (int b = 0; b < 8; b++) out[(size_t)b * D + j] = acc[b] + bj;
  }
}

extern "C" void kernel_launch(void* const* d_in, const int* in_sizes, int n_in,
                              void* d_out, int out_size, void* d_ws, size_t ws_size,
                              hipStream_t stream) {
  const float* x = (const float*)d_in[0];
  const float* query = (const float*)d_in[1];
  const float* norm_g = (const float*)d_in[2];
  const float* norm_b = (const float*)d_in[3];
  const float* nq_g = (const float*)d_in[4];
  const float* nq_b = (const float*)d_in[5];
  const float* nk_g = (const float*)d_in[6];
  const float* nk_b = (const float*)d_in[7];
  const float* nv_g = (const float*)d_in[8];
  const float* nv_b = (const float*)d_in[9];
  const float* no_g = (const float*)d_in[10];
  const float* no_b = (const float*)d_in[11];
  const float* Wq = (const float*)d_in[12];
  const float* bq = (const float*)d_in[13];
  const float* Wk = (const float*)d_in[14];
  // d_in[15] = bk: constant per (b,h) in scores -> cancels in softmax
  const float* Wv = (const float*)d_in[16];
  const float* bv = (const float*)d_in[17];
  const float* Wo = (const float*)d_in[18];
  const float* bo = (const float*)d_in[19];

  char* ws = (char*)d_ws;
  float* qn = (float*)(ws + 0);
  float* qv = (float*)(ws + 4096);
  float* Uf = (float*)(ws + 8192);
  h2* C1h = (h2*)(ws + 73728);
  h2* g1h = (h2*)(ws + 106496);
  h2* b1h = (h2*)(ws + 108544);
  float* hc = (float*)(ws + 110592);
  float* sconst = (float*)(ws + 110848);
  float* gmax = (float*)(ws + 110912);
  float* ginv = (float*)(ws + 111424);
  float* pmax = (float*)(ws + 111936);
  float* psum = (float*)(ws + 120128);
  float* stats = (float*)(ws + 128320);
  float* sc = (float*)(ws + 1176896);
  float* wsum = (float*)(ws + 5371200);
  float* av = (float*)(ws + 5895488);
  float* yb = (float*)(ws + 5928256);
  float* part = (float*)(ws + 5961024);

  int CH = 64;
  while (CH > 1 && 5961024ull + (size_t)B * CH * H * D * 4 > ws_size) CH >>= 1;
  const int RPC = S / CH;

  k_ln256<<<1, 256, 0, stream>>>(query, nq_g, nq_b, qn);
  k_qproj<<<256, 256, 0, stream>>>(qn, Wq, bq, qv);
  k_uproj<<<64, 256, 0, stream>>>(qv, Wk, Uf);
  k_prep0<<<1, 256, 0, stream>>>(norm_g, norm_b, g1h, b1h, sconst);
  k_prep1<<<16, 256, 0, stream>>>(Uf, norm_g, norm_b, nk_g, nk_b, C1h, hc);
  k_scores<<<1024, 256, 0, stream>>>(x, C1h, g1h, b1h, hc, sconst, stats, sc);
  k_smax1<<<128, 256, 0, stream>>>(sc, pmax, psum);
  k_smax2<<<1, 128, 0, stream>>>(pmax, psum, gmax, ginv);
  k_smax3<<<256, 256, 0, stream>>>(sc, gmax, ginv);
  k_accv<<<B * CH, 512, 0, stream>>>(x, stats, sc, norm_g, norm_b, nv_g, nv_b, part,
                                     CH, RPC);
  k_redpart<<<128, 256, 0, stream>>>(part, wsum, CH);
  k_proj8<<<1024, 64, 0, stream>>>(wsum, Wv, bv, av, H * D, D);  // V-proj on pooled
  k_proj8<<<1024, 64, 0, stream>>>(av, Wo, bo, yb, D, 0);        // O-proj
  k_ln256<<<8, 256, 0, stream>>>(yb, no_g, no_b, (float*)d_out);
}

// Round 7
// 184.098 us; speedup vs baseline: 2.8004x; 1.0015x over previous
//
#include <hip/hip_runtime.h>
#include <math.h>

#define D 1024
#define S 8192
#define B 8
#define H 16
#define NROWS (B * S)
#define EPS_LN 1e-5f

typedef _Float16 h2 __attribute__((ext_vector_type(2)));

__device__ __forceinline__ float wred_sum(float v) {
#pragma unroll
  for (int m = 1; m < 64; m <<= 1) v += __shfl_xor(v, m, 64);
  return v;
}
__device__ __forceinline__ float wred_max(float v) {
#pragma unroll
  for (int m = 1; m < 64; m <<= 1) v = fmaxf(v, __shfl_xor(v, m, 64));
  return v;
}
__device__ __forceinline__ h2 pkh(float a, float b) {
#if __has_builtin(__builtin_amdgcn_cvt_pkrtz)
  return __builtin_bit_cast(h2, __builtin_amdgcn_cvt_pkrtz(a, b));
#else
  h2 r; r.x = (_Float16)a; r.y = (_Float16)b; return r;
#endif
}
__device__ __forceinline__ float fdot2(h2 a, h2 b, float c) {
#if __has_builtin(__builtin_amdgcn_fdot2)
  typedef __fp16 fp16v2 __attribute__((ext_vector_type(2)));
  return __builtin_amdgcn_fdot2(__builtin_bit_cast(fp16v2, a),
                                __builtin_bit_cast(fp16v2, b), c, false);
#else
  return c + (float)a.x * (float)b.x + (float)a.y * (float)b.y;
#endif
}
__device__ __forceinline__ h2 bch(unsigned int u) { return __builtin_bit_cast(h2, u); }

// ---------- LN over one 1024-row per block (256 thr) ----------
__global__ void k_ln256(const float* __restrict__ in, const float* __restrict__ g,
                        const float* __restrict__ bb, float* __restrict__ out) {
  const int b = blockIdx.x, t = threadIdx.x;
  float4 v = ((const float4*)(in + (size_t)b * D))[t];
  float s = v.x + v.y + v.z + v.w;
  float s2 = fmaf(v.x, v.x, fmaf(v.y, v.y, fmaf(v.z, v.z, v.w * v.w)));
  __shared__ float red[8];
  float ws = wred_sum(s), ws2 = wred_sum(s2);
  const int lane = t & 63, wv = t >> 6;
  if (!lane) { red[wv] = ws; red[wv + 4] = ws2; }
  __syncthreads();
  ws = red[0] + red[1] + red[2] + red[3];
  ws2 = red[4] + red[5] + red[6] + red[7];
  const float m = ws * (1.f / D);
  const float rs = rsqrtf(ws2 * (1.f / D) - m * m + EPS_LN);
  const float4 gg = ((const float4*)g)[t], bv = ((const float4*)bb)[t];
  float4 o;
  o.x = (v.x - m) * rs * gg.x + bv.x;
  o.y = (v.y - m) * rs * gg.y + bv.y;
  o.z = (v.z - m) * rs * gg.z + bv.z;
  o.w = (v.w - m) * rs * gg.w + bv.w;
  ((float4*)(out + (size_t)b * D))[t] = o;
}

// ---------- q[j] = qn . Wq[j,:] + bq[j] : one wave per j ----------
__global__ void k_qproj(const float* __restrict__ qn, const float* __restrict__ Wq,
                        const float* __restrict__ bq, float* __restrict__ q) {
  const int wv = threadIdx.x >> 6, lane = threadIdx.x & 63;
  const int j = blockIdx.x * 4 + wv;
  const float4* wr = (const float4*)(Wq + (size_t)j * D);
  const float4* qr = (const float4*)qn;
  float acc = 0.f;
#pragma unroll
  for (int k = 0; k < 4; k++) {
    float4 a = qr[lane + 64 * k], w = wr[lane + 64 * k];
    acc = fmaf(a.x, w.x, acc); acc = fmaf(a.y, w.y, acc);
    acc = fmaf(a.z, w.z, acc); acc = fmaf(a.w, w.w, acc);
  }
  acc = wred_sum(acc);
  if (!lane) q[j] = acc + bq[j];
}

// ---------- Uf[h][d] = scale * sum_e q[h*64+e] * Wk[h*64+e][d] (fp32) ----------
__global__ void k_uproj(const float* __restrict__ q, const float* __restrict__ Wk,
                        float* __restrict__ Uf) {
  const int idx = blockIdx.x * 256 + threadIdx.x;
  const int h = idx >> 10, d = idx & (D - 1);
  float acc = 0.f;
#pragma unroll 4
  for (int e = 0; e < 64; e++)
    acc = fmaf(q[h * 64 + e], Wk[(size_t)(h * 64 + e) * D + d], acc);
  Uf[idx] = acc * 0.125f;  // 1/sqrt(64)
}

// ---------- prep0: f16 packs of g1/b1 + 5 weight scalars ----------
__global__ void k_prep0(const float* __restrict__ g, const float* __restrict__ b,
                        h2* __restrict__ g1h, h2* __restrict__ b1h,
                        float* __restrict__ sconst) {
  const int t = threadIdx.x;
  float4 gv = ((const float4*)g)[t], bv = ((const float4*)b)[t];
  g1h[2 * t] = pkh(gv.x, gv.y); g1h[2 * t + 1] = pkh(gv.z, gv.w);
  b1h[2 * t] = pkh(bv.x, bv.y); b1h[2 * t + 1] = pkh(bv.z, bv.w);
  float sg = gv.x + gv.y + gv.z + gv.w;
  float sb = bv.x + bv.y + bv.z + bv.w;
  float sbb = bv.x * bv.x + bv.y * bv.y + bv.z * bv.z + bv.w * bv.w;
  float sgb = gv.x * bv.x + gv.y * bv.y + gv.z * bv.z + gv.w * bv.w;
  float sgg = gv.x * gv.x + gv.y * gv.y + gv.z * gv.z + gv.w * gv.w;
  __shared__ float red[4][5];
  sg = wred_sum(sg); sb = wred_sum(sb); sbb = wred_sum(sbb);
  sgb = wred_sum(sgb); sgg = wred_sum(sgg);
  const int lane = t & 63, wv = t >> 6;
  if (!lane) { red[wv][0] = sg; red[wv][1] = sb; red[wv][2] = sbb; red[wv][3] = sgb; red[wv][4] = sgg; }
  __syncthreads();
  if (t < 5) {
    float a = red[0][t] + red[1][t] + red[2][t] + red[3][t];
    sconst[t] = a;
  }
}

// ---------- prep1: C1h = f16(U*g1*kg) + per-head consts c2..c5 ----------
__global__ void k_prep1(const float* __restrict__ Uf, const float* __restrict__ g1,
                        const float* __restrict__ b1, const float* __restrict__ kg,
                        const float* __restrict__ kb, h2* __restrict__ C1h,
                        float* __restrict__ hc) {
  const int h = blockIdx.x, t = threadIdx.x;
  const float4 u = ((const float4*)(Uf + (size_t)h * D))[t];
  const float4 gv = ((const float4*)g1)[t], bv = ((const float4*)b1)[t];
  const float4 kgv = ((const float4*)kg)[t], kbv = ((const float4*)kb)[t];
  const float e0 = u.x * gv.x * kgv.x, e1 = u.y * gv.y * kgv.y;
  const float e2 = u.z * gv.z * kgv.z, e3 = u.w * gv.w * kgv.w;
  C1h[h * 512 + 2 * t] = pkh(e0, e1);
  C1h[h * 512 + 2 * t + 1] = pkh(e2, e3);
  float p2 = u.x * kgv.x * bv.x + u.y * kgv.y * bv.y + u.z * kgv.z * bv.z + u.w * kgv.w * bv.w;
  float p3 = e0 + e1 + e2 + e3;
  float p4 = u.x * kgv.x + u.y * kgv.y + u.z * kgv.z + u.w * kgv.w;
  float p5 = u.x * kbv.x + u.y * kbv.y + u.z * kbv.z + u.w * kbv.w;
  __shared__ float red[4][4];
  p2 = wred_sum(p2); p3 = wred_sum(p3); p4 = wred_sum(p4); p5 = wred_sum(p5);
  const int lane = t & 63, wv = t >> 6;
  if (!lane) { red[wv][0] = p2; red[wv][1] = p3; red[wv][2] = p4; red[wv][3] = p5; }
  __syncthreads();
  if (t < 4) {
    float a = red[0][t] + red[1][t] + red[2][t] + red[3][t];
    hc[t * 16 + h] = a;
  }
}

// ---------- pass 1 over x: fused LN-LN-scores via affine trick ----------
// 16 lanes per row, 4 rows per wave; chunk-streaming; 4 waves/SIMD target
__global__ __launch_bounds__(256, 4) void k_scores(
    const float* __restrict__ x, const h2* __restrict__ C1h,
    const h2* __restrict__ g1h, const h2* __restrict__ b1h,
    const float* __restrict__ hc, const float* __restrict__ sconst,
    float* __restrict__ stats, float* __restrict__ sc) {
  __shared__ __align__(16) h2 sC[16 * 512];  // 32 KB  [h][pair]
  __shared__ __align__(16) h2 sG[512], sB[512];
  {
    const uint4* src = (const uint4*)C1h;
    uint4* dst = (uint4*)sC;
    for (int i = threadIdx.x; i < 2048; i += 256) dst[i] = src[i];
    if (threadIdx.x < 128) {
      ((uint4*)sG)[threadIdx.x] = ((const uint4*)g1h)[threadIdx.x];
      ((uint4*)sB)[threadIdx.x] = ((const uint4*)b1h)[threadIdx.x];
    }
  }
  __syncthreads();
  const int lane = threadIdx.x & 63, wv = threadIdx.x >> 6;
  const int g = lane >> 4, j = lane & 15;
  const float c2 = hc[j], c3 = hc[16 + j], c4 = hc[32 + j], c5 = hc[48 + j];
  const float Sg1 = sconst[0], Sb1 = sconst[1], Sbb = sconst[2];
  const float Sgb = sconst[3], Sgg = sconst[4];
  const h2 one = {(_Float16)1.f, (_Float16)1.f};
  const int wid = blockIdx.x * 4 + wv;
#pragma unroll 1
  for (int i = 0; i < 4; i++) {
    const int r = wid * 16 + i * 4 + g;
    const float* xr = x + (size_t)r * D + 8 * j;  // lane cols: 8j..8j+7 per 128-chunk
    float p[16];
#pragma unroll
    for (int h = 0; h < 16; h++) p[h] = 0.f;
    float S0 = 0, S1 = 0, Sa = 0, Sb = 0, Sc = 0, Sd = 0;
#pragma unroll 2
    for (int c = 0; c < 8; c++) {
      const float4 a = *(const float4*)(xr + 128 * c);
      const float4 b = *(const float4*)(xr + 128 * c + 4);
      const h2 p0 = pkh(a.x, a.y), p1 = pkh(a.z, a.w);
      const h2 p2 = pkh(b.x, b.y), p3 = pkh(b.z, b.w);
      const uint4 gu = ((const uint4*)sG)[16 * c + j];
      const uint4 bu = ((const uint4*)sB)[16 * c + j];
      const h2 g0 = bch(gu.x), g1p = bch(gu.y), g2 = bch(gu.z), g3 = bch(gu.w);
      const h2 b0 = bch(bu.x), b1p = bch(bu.y), b2 = bch(bu.z), b3 = bch(bu.w);
      S0 = fdot2(p0, one, S0); S0 = fdot2(p1, one, S0);
      S0 = fdot2(p2, one, S0); S0 = fdot2(p3, one, S0);
      S1 = fdot2(p0, p0, S1); S1 = fdot2(p1, p1, S1);
      S1 = fdot2(p2, p2, S1); S1 = fdot2(p3, p3, S1);
      Sa = fdot2(g0, p0, Sa); Sa = fdot2(g1p, p1, Sa);
      Sa = fdot2(g2, p2, Sa); Sa = fdot2(g3, p3, Sa);
      const h2 gx0 = g0 * p0, gx1 = g1p * p1, gx2 = g2 * p2, gx3 = g3 * p3;
      Sb = fdot2(g0, gx0, Sb); Sb = fdot2(g1p, gx1, Sb);
      Sb = fdot2(g2, gx2, Sb); Sb = fdot2(g3, gx3, Sb);
      Sc = fdot2(gx0, gx0, Sc); Sc = fdot2(gx1, gx1, Sc);
      Sc = fdot2(gx2, gx2, Sc); Sc = fdot2(gx3, gx3, Sc);
      Sd = fdot2(b0, gx0, Sd); Sd = fdot2(b1p, gx1, Sd);
      Sd = fdot2(b2, gx2, Sd); Sd = fdot2(b3, gx3, Sd);
      // head dots for this chunk (x stays in p0..p3 regs, no array)
#pragma unroll
      for (int h = 0; h < 16; h++) {
        const uint4 u = ((const uint4*)sC)[h * 128 + 16 * c + j];
        float acc = p[h];
        acc = fdot2(bch(u.x), p0, acc);
        acc = fdot2(bch(u.y), p1, acc);
        acc = fdot2(bch(u.z), p2, acc);
        acc = fdot2(bch(u.w), p3, acc);
        p[h] = acc;
      }
    }
    // stats butterfly within 16-lane group
#pragma unroll
    for (int m = 1; m < 16; m <<= 1) {
      S0 += __shfl_xor(S0, m, 64); S1 += __shfl_xor(S1, m, 64);
      Sa += __shfl_xor(Sa, m, 64); Sb += __shfl_xor(Sb, m, 64);
      Sc += __shfl_xor(Sc, m, 64); Sd += __shfl_xor(Sd, m, 64);
    }
    // transpose-reduce: lane j ends with sum over group of p[j]
    float q8[8];
#pragma unroll
    for (int h = 0; h < 8; h++) {
      const float a = p[2 * h], bb = p[2 * h + 1];
      const float sent = (j & 1) ? a : bb;
      const float keep = (j & 1) ? bb : a;
      q8[h] = keep + __shfl_xor(sent, 1, 64);
    }
    float q4[4];
#pragma unroll
    for (int h = 0; h < 4; h++) {
      const float a = q8[2 * h], bb = q8[2 * h + 1];
      const float sent = (j & 2) ? a : bb;
      const float keep = (j & 2) ? bb : a;
      q4[h] = keep + __shfl_xor(sent, 2, 64);
    }
    float q2[2];
#pragma unroll
    for (int h = 0; h < 2; h++) {
      const float a = q4[2 * h], bb = q4[2 * h + 1];
      const float sent = (j & 4) ? a : bb;
      const float keep = (j & 4) ? bb : a;
      q2[h] = keep + __shfl_xor(sent, 4, 64);
    }
    float q1;
    {
      const float a = q2[0], bb = q2[1];
      const float sent = (j & 8) ? a : bb;
      const float keep = (j & 8) ? bb : a;
      q1 = keep + __shfl_xor(sent, 8, 64);
    }
    // final scalars
    const float m1 = S0 * (1.f / D);
    const float rs1 = rsqrtf(S1 * (1.f / D) - m1 * m1 + EPS_LN);
    const float m2 = (rs1 * (Sa - m1 * Sg1) + Sb1) * (1.f / D);
    const float sxn2 = rs1 * rs1 * Sc + 2.f * rs1 * (Sd - m1 * rs1 * Sb) +
                       (Sbb - 2.f * m1 * rs1 * Sgb + m1 * m1 * rs1 * rs1 * Sgg);
    const float rs2 = rsqrtf(sxn2 * (1.f / D) - m2 * m2 + EPS_LN);
    if (j == 0) ((float4*)stats)[r] = make_float4(m1, rs1, m2, rs2);
    const float rs12 = rs1 * rs2;
    sc[(size_t)r * 16 + j] = rs12 * q1 - rs12 * m1 * c3 + rs2 * (c2 - m2 * c4) + c5;
  }
}

// ---------- softmax stage 1: per-chunk max + sum(exp(v-max)) ----------
__global__ void k_smax1(const float* __restrict__ sc, float* __restrict__ pmax,
                        float* __restrict__ psum) {
  const int blk = blockIdx.x, t = threadIdx.x;
  const int b = blk >> 4, c = blk & 15;
  const int r0 = b * S + c * 512;
  __shared__ float lM[4][16], lS[4][16];
  float mx[16];
#pragma unroll
  for (int h = 0; h < 16; h++) mx[h] = -3.4e38f;
#pragma unroll
  for (int rr = 0; rr < 2; rr++) {
    const float4* row = (const float4*)(sc + (size_t)(r0 + t + 256 * rr) * 16);
    const float4 v0 = row[0], v1 = row[1], v2 = row[2], v3 = row[3];
    mx[0] = fmaxf(mx[0], v0.x); mx[1] = fmaxf(mx[1], v0.y);
    mx[2] = fmaxf(mx[2], v0.z); mx[3] = fmaxf(mx[3], v0.w);
    mx[4] = fmaxf(mx[4], v1.x); mx[5] = fmaxf(mx[5], v1.y);
    mx[6] = fmaxf(mx[6], v1.z); mx[7] = fmaxf(mx[7], v1.w);
    mx[8] = fmaxf(mx[8], v2.x); mx[9] = fmaxf(mx[9], v2.y);
    mx[10] = fmaxf(mx[10], v2.z); mx[11] = fmaxf(mx[11], v2.w);
    mx[12] = fmaxf(mx[12], v3.x); mx[13] = fmaxf(mx[13], v3.y);
    mx[14] = fmaxf(mx[14], v3.z); mx[15] = fmaxf(mx[15], v3.w);
  }
  const int lane = t & 63, wv = t >> 6;
#pragma unroll
  for (int h = 0; h < 16; h++) mx[h] = wred_max(mx[h]);
  if (!lane) {
#pragma unroll
    for (int h = 0; h < 16; h++) lM[wv][h] = mx[h];
  }
  __syncthreads();
  float M[16];
#pragma unroll
  for (int h = 0; h < 16; h++)
    M[h] = fmaxf(fmaxf(lM[0][h], lM[1][h]), fmaxf(lM[2][h], lM[3][h]));
  float sm[16];
#pragma unroll
  for (int h = 0; h < 16; h++) sm[h] = 0.f;
#pragma unroll
  for (int rr = 0; rr < 2; rr++) {
    const float4* row = (const float4*)(sc + (size_t)(r0 + t + 256 * rr) * 16);
    const float4 v0 = row[0], v1 = row[1], v2 = row[2], v3 = row[3];
    sm[0] += __expf(v0.x - M[0]); sm[1] += __expf(v0.y - M[1]);
    sm[2] += __expf(v0.z - M[2]); sm[3] += __expf(v0.w - M[3]);
    sm[4] += __expf(v1.x - M[4]); sm[5] += __expf(v1.y - M[5]);
    sm[6] += __expf(v1.z - M[6]); sm[7] += __expf(v1.w - M[7]);
    sm[8] += __expf(v2.x - M[8]); sm[9] += __expf(v2.y - M[9]);
    sm[10] += __expf(v2.z - M[10]); sm[11] += __expf(v2.w - M[11]);
    sm[12] += __expf(v3.x - M[12]); sm[13] += __expf(v3.y - M[13]);
    sm[14] += __expf(v3.z - M[14]); sm[15] += __expf(v3.w - M[15]);
  }
#pragma unroll
  for (int h = 0; h < 16; h++) sm[h] = wred_sum(sm[h]);
  if (!lane) {
#pragma unroll
    for (int h = 0; h < 16; h++) lS[wv][h] = sm[h];
  }
  __syncthreads();
  if (t < 16) {
    float m = fmaxf(fmaxf(lM[0][t], lM[1][t]), fmaxf(lM[2][t], lM[3][t]));
    float s = lS[0][t] + lS[1][t] + lS[2][t] + lS[3][t];
    pmax[blk * 16 + t] = m;
    psum[blk * 16 + t] = s;
  }
}

// ---------- softmax stage 2: combine 16 chunks per (b,h) ----------
__global__ void k_smax2(const float* __restrict__ pmax, const float* __restrict__ psum,
                        float* __restrict__ gmax, float* __restrict__ ginv) {
  const int t = threadIdx.x;  // 128 = B*H
  const int b = t >> 4, h = t & 15;
  float M = -3.4e38f;
  for (int c = 0; c < 16; c++) M = fmaxf(M, pmax[(b * 16 + c) * 16 + h]);
  float sum = 0.f;
  for (int c = 0; c < 16; c++)
    sum += psum[(b * 16 + c) * 16 + h] * __expf(pmax[(b * 16 + c) * 16 + h] - M);
  gmax[t] = M;
  ginv[t] = 1.f / (sum + 1e-9f);
}

// ---------- softmax stage 3: materialize attn in place ----------
__global__ void k_smax3(float* __restrict__ sc, const float* __restrict__ gmax,
                        const float* __restrict__ ginv) {
  const int r = blockIdx.x * 256 + threadIdx.x;
  const int b = r >> 13;
  float4 M[4], I[4];
#pragma unroll
  for (int k = 0; k < 4; k++) {
    M[k] = ((const float4*)(gmax + b * 16))[k];
    I[k] = ((const float4*)(ginv + b * 16))[k];
  }
  float4* row = (float4*)(sc + (size_t)r * 16);
#pragma unroll
  for (int k = 0; k < 4; k++) {
    float4 v = row[k];
    v.x = fminf(fmaxf(__expf(v.x - M[k].x) * I[k].x, 1e-9f), 1.f);
    v.y = fminf(fmaxf(__expf(v.y - M[k].y) * I[k].y, 1e-9f), 1.f);
    v.z = fminf(fmaxf(__expf(v.z - M[k].z) * I[k].z, 1e-9f), 1.f);
    v.w = fminf(fmaxf(__expf(v.w - M[k].w) * I[k].w, 1e-9f), 1.f);
    row[k] = v;
  }
}

// ---------- pass 2 over x: vn recompute + attn-weighted column accumulate ----------
__global__ __launch_bounds__(512) void k_accv(
    const float* __restrict__ x, const float* __restrict__ stats,
    const float* __restrict__ attn,
    const float* __restrict__ g1, const float* __restrict__ b1,
    const float* __restrict__ vg, const float* __restrict__ vb,
    float* __restrict__ part, int CH, int RPC) {
  const int b = blockIdx.x / CH, ch = blockIdx.x % CH;
  const int c0 = threadIdx.x * 2;
  const float2 gv = *(const float2*)(g1 + c0), bv = *(const float2*)(b1 + c0);
  const float2 vgv = *(const float2*)(vg + c0), vbv = *(const float2*)(vb + c0);
  float acc0[16], acc1[16];
#pragma unroll
  for (int h = 0; h < 16; h++) { acc0[h] = 0.f; acc1[h] = 0.f; }
  const int r0 = b * S + ch * RPC;
#pragma unroll 2
  for (int i = 0; i < RPC; i++) {
    const int r = r0 + i;
    const float4 st = ((const float4*)stats)[r];  // m1 rs1 m2 rs2
    const float2 xv = *(const float2*)(x + (size_t)r * D + c0);
    const float4* wr = (const float4*)(attn + (size_t)r * 16);
    const float4 w0 = wr[0], w1 = wr[1], w2 = wr[2], w3 = wr[3];
    float xn0 = (xv.x - st.x) * st.y * gv.x + bv.x;
    float xn1 = (xv.y - st.x) * st.y * gv.y + bv.y;
    const float v0 = (xn0 - st.z) * st.w * vgv.x + vbv.x;
    const float v1 = (xn1 - st.z) * st.w * vgv.y + vbv.y;
    acc0[0] = fmaf(w0.x, v0, acc0[0]);   acc1[0] = fmaf(w0.x, v1, acc1[0]);
    acc0[1] = fmaf(w0.y, v0, acc0[1]);   acc1[1] = fmaf(w0.y, v1, acc1[1]);
    acc0[2] = fmaf(w0.z, v0, acc0[2]);   acc1[2] = fmaf(w0.z, v1, acc1[2]);
    acc0[3] = fmaf(w0.w, v0, acc0[3]);   acc1[3] = fmaf(w0.w, v1, acc1[3]);
    acc0[4] = fmaf(w1.x, v0, acc0[4]);   acc1[4] = fmaf(w1.x, v1, acc1[4]);
    acc0[5] = fmaf(w1.y, v0, acc0[5]);   acc1[5] = fmaf(w1.y, v1, acc1[5]);
    acc0[6] = fmaf(w1.z, v0, acc0[6]);   acc1[6] = fmaf(w1.z, v1, acc1[6]);
    acc0[7] = fmaf(w1.w, v0, acc0[7]);   acc1[7] = fmaf(w1.w, v1, acc1[7]);
    acc0[8] = fmaf(w2.x, v0, acc0[8]);   acc1[8] = fmaf(w2.x, v1, acc1[8]);
    acc0[9] = fmaf(w2.y, v0, acc0[9]);   acc1[9] = fmaf(w2.y, v1, acc1[9]);
    acc0[10] = fmaf(w2.z, v0, acc0[10]); acc1[10] = fmaf(w2.z, v1, acc1[10]);
    acc0[11] = fmaf(w2.w, v0, acc0[11]); acc1[11] = fmaf(w2.w, v1, acc1[11]);
    acc0[12] = fmaf(w3.x, v0, acc0[12]); acc1[12] = fmaf(w3.x, v1, acc1[12]);
    acc0[13] = fmaf(w3.y, v0, acc0[13]); acc1[13] = fmaf(w3.y, v1, acc1[13]);
    acc0[14] = fmaf(w3.z, v0, acc0[14]); acc1[14] = fmaf(w3.z, v1, acc1[14]);
    acc0[15] = fmaf(w3.w, v0, acc0[15]); acc1[15] = fmaf(w3.w, v1, acc1[15]);
  }
  float* po = part + (size_t)blockIdx.x * (H * D);
#pragma unroll
  for (int h = 0; h < 16; h++)
    *(float2*)(po + h * D + c0) = make_float2(acc0[h], acc1[h]);
}

// ---------- reduce chunk partials -> wsum[b][h][d] ----------
__global__ void k_redpart(const float* __restrict__ part, float* __restrict__ wsum,
                          int CH) {
  const int b = blockIdx.x >> 4, h = blockIdx.x & 15;
  const int d = threadIdx.x * 4;
  float4 a = make_float4(0.f, 0.f, 0.f, 0.f);
  for (int k = 0; k < CH; k++) {
    const float4 p = *(const float4*)(part + ((size_t)(b * CH + k) * H + h) * D + d);
    a.x += p.x; a.y += p.y; a.z += p.z; a.w += p.w;
  }
  *(float4*)(wsum + ((size_t)b * H + h) * D + d) = a;
}

// ---------- out[b][j] = W[j,:] . src[b, (maybe head-sliced)] + bias[j] ----------
__global__ void k_proj8(const float* __restrict__ src, const float* __restrict__ W,
                        const float* __restrict__ bias, float* __restrict__ out,
                        int bstride, int hstride) {
  const int j = blockIdx.x, lane = threadIdx.x;
  const int h = j >> 6;
  const float4* wr = (const float4*)(W + (size_t)j * D);
  float acc[8];
#pragma unroll
  for (int b = 0; b < 8; b++) acc[b] = 0.f;
#pragma unroll
  for (int k = 0; k < 4; k++) {
    const float4 w4 = wr[lane + 64 * k];
#pragma unroll
    for (int b = 0; b < 8; b++) {
      const float4 s4 =
          ((const float4*)(src + (size_t)b * bstride + (size_t)h * hstride))[lane + 64 * k];
      acc[b] = fmaf(w4.x, s4.x, acc[b]); acc[b] = fmaf(w4.y, s4.y, acc[b]);
      acc[b] = fmaf(w4.z, s4.z, acc[b]); acc[b] = fmaf(w4.w, s4.w, acc[b]);
    }
  }
#pragma unroll
  for (int b = 0; b < 8; b++) acc[b] = wred_sum(acc[b]);
  if (!lane) {
    const float bj = bias[j];
#pragma unroll
    for (int b = 0; b < 8; b++) out[(size_t)b * D + j] = acc[b] + bj;
  }
}

extern "C" void kernel_launch(void* const* d_in, const int* in_sizes, int n_in,
                              void* d_out, int out_size, void* d_ws, size_t ws_size,
                              hipStream_t stream) {
  const float* x = (const float*)d_in[0];
  const float* query = (const float*)d_in[1];
  const float* norm_g = (const float*)d_in[2];
  const float* norm_b = (const float*)d_in[3];
  const float* nq_g = (const float*)d_in[4];
  const float* nq_b = (const float*)d_in[5];
  const float* nk_g = (const float*)d_in[6];
  const float* nk_b = (const float*)d_in[7];
  const float* nv_g = (const float*)d_in[8];
  const float* nv_b = (const float*)d_in[9];
  const float* no_g = (const float*)d_in[10];
  const float* no_b = (const float*)d_in[11];
  const float* Wq = (const float*)d_in[12];
  const float* bq = (const float*)d_in[13];
  const float* Wk = (const float*)d_in[14];
  // d_in[15] = bk: constant per (b,h) in scores -> cancels in softmax
  const float* Wv = (const float*)d_in[16];
  const float* bv = (const float*)d_in[17];
  const float* Wo = (const float*)d_in[18];
  const float* bo = (const float*)d_in[19];

  char* ws = (char*)d_ws;
  float* qn = (float*)(ws + 0);
  float* qv = (float*)(ws + 4096);
  float* Uf = (float*)(ws + 8192);
  h2* C1h = (h2*)(ws + 73728);
  h2* g1h = (h2*)(ws + 106496);
  h2* b1h = (h2*)(ws + 108544);
  float* hc = (float*)(ws + 110592);
  float* sconst = (float*)(ws + 110848);
  float* gmax = (float*)(ws + 110912);
  float* ginv = (float*)(ws + 111424);
  float* pmax = (float*)(ws + 111936);
  float* psum = (float*)(ws + 120128);
  float* stats = (float*)(ws + 128320);
  float* sc = (float*)(ws + 1176896);
  float* wsum = (float*)(ws + 5371200);
  float* av = (float*)(ws + 5895488);
  float* yb = (float*)(ws + 5928256);
  float* part = (float*)(ws + 5961024);

  int CH = 64;
  while (CH > 1 && 5961024ull + (size_t)B * CH * H * D * 4 > ws_size) CH >>= 1;
  const int RPC = S / CH;

  k_ln256<<<1, 256, 0, stream>>>(query, nq_g, nq_b, qn);
  k_qproj<<<256, 256, 0, stream>>>(qn, Wq, bq, qv);
  k_uproj<<<64, 256, 0, stream>>>(qv, Wk, Uf);
  k_prep0<<<1, 256, 0, stream>>>(norm_g, norm_b, g1h, b1h, sconst);
  k_prep1<<<16, 256, 0, stream>>>(Uf, norm_g, norm_b, nk_g, nk_b, C1h, hc);
  k_scores<<<1024, 256, 0, stream>>>(x, C1h, g1h, b1h, hc, sconst, stats, sc);
  k_smax1<<<128, 256, 0, stream>>>(sc, pmax, psum);
  k_smax2<<<1, 128, 0, stream>>>(pmax, psum, gmax, ginv);
  k_smax3<<<256, 256, 0, stream>>>(sc, gmax, ginv);
  k_accv<<<B * CH, 512, 0, stream>>>(x, stats, sc, norm_g, norm_b, nv_g, nv_b, part,
                                     CH, RPC);
  k_redpart<<<128, 256, 0, stream>>>(part, wsum, CH);
  k_proj8<<<1024, 64, 0, stream>>>(wsum, Wv, bv, av, H * D, D);  // V-proj on pooled
  k_proj8<<<1024, 64, 0, stream>>>(av, Wo, bo, yb, D, 0);        // O-proj
  k_ln256<<<8, 256, 0, stream>>>(yb, no_g, no_b, (float*)d_out);
}

// Round 8
// 180.182 us; speedup vs baseline: 2.8613x; 1.0217x over previous
//
#include <hip/hip_runtime.h>
#include <math.h>

#define D 1024
#define S 8192
#define B 8
#define H 16
#define NROWS (B * S)
#define EPS_LN 1e-5f

typedef _Float16 h2 __attribute__((ext_vector_type(2)));

__device__ __forceinline__ float wred_sum(float v) {
#pragma unroll
  for (int m = 1; m < 64; m <<= 1) v += __shfl_xor(v, m, 64);
  return v;
}
__device__ __forceinline__ float wred_max(float v) {
#pragma unroll
  for (int m = 1; m < 64; m <<= 1) v = fmaxf(v, __shfl_xor(v, m, 64));
  return v;
}
__device__ __forceinline__ h2 pkh(float a, float b) {
#if __has_builtin(__builtin_amdgcn_cvt_pkrtz)
  return __builtin_bit_cast(h2, __builtin_amdgcn_cvt_pkrtz(a, b));
#else
  h2 r; r.x = (_Float16)a; r.y = (_Float16)b; return r;
#endif
}
__device__ __forceinline__ float fdot2(h2 a, h2 b, float c) {
#if __has_builtin(__builtin_amdgcn_fdot2)
  typedef __fp16 fp16v2 __attribute__((ext_vector_type(2)));
  return __builtin_amdgcn_fdot2(__builtin_bit_cast(fp16v2, a),
                                __builtin_bit_cast(fp16v2, b), c, false);
#else
  return c + (float)a.x * (float)b.x + (float)a.y * (float)b.y;
#endif
}
__device__ __forceinline__ h2 bch(unsigned int u) { return __builtin_bit_cast(h2, u); }

// ---------- LN over one 1024-row per block (256 thr) ----------
__global__ void k_ln256(const float* __restrict__ in, const float* __restrict__ g,
                        const float* __restrict__ bb, float* __restrict__ out) {
  const int b = blockIdx.x, t = threadIdx.x;
  float4 v = ((const float4*)(in + (size_t)b * D))[t];
  float s = v.x + v.y + v.z + v.w;
  float s2 = fmaf(v.x, v.x, fmaf(v.y, v.y, fmaf(v.z, v.z, v.w * v.w)));
  __shared__ float red[8];
  float ws = wred_sum(s), ws2 = wred_sum(s2);
  const int lane = t & 63, wv = t >> 6;
  if (!lane) { red[wv] = ws; red[wv + 4] = ws2; }
  __syncthreads();
  ws = red[0] + red[1] + red[2] + red[3];
  ws2 = red[4] + red[5] + red[6] + red[7];
  const float m = ws * (1.f / D);
  const float rs = rsqrtf(ws2 * (1.f / D) - m * m + EPS_LN);
  const float4 gg = ((const float4*)g)[t], bv = ((const float4*)bb)[t];
  float4 o;
  o.x = (v.x - m) * rs * gg.x + bv.x;
  o.y = (v.y - m) * rs * gg.y + bv.y;
  o.z = (v.z - m) * rs * gg.z + bv.z;
  o.w = (v.w - m) * rs * gg.w + bv.w;
  ((float4*)(out + (size_t)b * D))[t] = o;
}

// ---------- q[j] = qn . Wq[j,:] + bq[j] : one wave per j ----------
__global__ void k_qproj(const float* __restrict__ qn, const float* __restrict__ Wq,
                        const float* __restrict__ bq, float* __restrict__ q) {
  const int wv = threadIdx.x >> 6, lane = threadIdx.x & 63;
  const int j = blockIdx.x * 4 + wv;
  const float4* wr = (const float4*)(Wq + (size_t)j * D);
  const float4* qr = (const float4*)qn;
  float acc = 0.f;
#pragma unroll
  for (int k = 0; k < 4; k++) {
    float4 a = qr[lane + 64 * k], w = wr[lane + 64 * k];
    acc = fmaf(a.x, w.x, acc); acc = fmaf(a.y, w.y, acc);
    acc = fmaf(a.z, w.z, acc); acc = fmaf(a.w, w.w, acc);
  }
  acc = wred_sum(acc);
  if (!lane) q[j] = acc + bq[j];
}

// ---------- Uf[h][d] = scale * sum_e q[h*64+e] * Wk[h*64+e][d] (fp32) ----------
__global__ void k_uproj(const float* __restrict__ q, const float* __restrict__ Wk,
                        float* __restrict__ Uf) {
  const int idx = blockIdx.x * 256 + threadIdx.x;
  const int h = idx >> 10, d = idx & (D - 1);
  float acc = 0.f;
#pragma unroll 4
  for (int e = 0; e < 64; e++)
    acc = fmaf(q[h * 64 + e], Wk[(size_t)(h * 64 + e) * D + d], acc);
  Uf[idx] = acc * 0.125f;  // 1/sqrt(64)
}

// ---------- prep0: f16 packs of g1/b1 + 5 weight scalars ----------
__global__ void k_prep0(const float* __restrict__ g, const float* __restrict__ b,
                        h2* __restrict__ g1h, h2* __restrict__ b1h,
                        float* __restrict__ sconst) {
  const int t = threadIdx.x;
  float4 gv = ((const float4*)g)[t], bv = ((const float4*)b)[t];
  g1h[2 * t] = pkh(gv.x, gv.y); g1h[2 * t + 1] = pkh(gv.z, gv.w);
  b1h[2 * t] = pkh(bv.x, bv.y); b1h[2 * t + 1] = pkh(bv.z, bv.w);
  float sg = gv.x + gv.y + gv.z + gv.w;
  float sb = bv.x + bv.y + bv.z + bv.w;
  float sbb = bv.x * bv.x + bv.y * bv.y + bv.z * bv.z + bv.w * bv.w;
  float sgb = gv.x * bv.x + gv.y * bv.y + gv.z * bv.z + gv.w * bv.w;
  float sgg = gv.x * gv.x + gv.y * gv.y + gv.z * gv.z + gv.w * gv.w;
  __shared__ float red[4][5];
  sg = wred_sum(sg); sb = wred_sum(sb); sbb = wred_sum(sbb);
  sgb = wred_sum(sgb); sgg = wred_sum(sgg);
  const int lane = t & 63, wv = t >> 6;
  if (!lane) { red[wv][0] = sg; red[wv][1] = sb; red[wv][2] = sbb; red[wv][3] = sgb; red[wv][4] = sgg; }
  __syncthreads();
  if (t < 5) {
    float a = red[0][t] + red[1][t] + red[2][t] + red[3][t];
    sconst[t] = a;
  }
}

// ---------- prep1: C1h = f16(U*g1*kg) + per-head consts c2..c5 ----------
__global__ void k_prep1(const float* __restrict__ Uf, const float* __restrict__ g1,
                        const float* __restrict__ b1, const float* __restrict__ kg,
                        const float* __restrict__ kb, h2* __restrict__ C1h,
                        float* __restrict__ hc) {
  const int h = blockIdx.x, t = threadIdx.x;
  const float4 u = ((const float4*)(Uf + (size_t)h * D))[t];
  const float4 gv = ((const float4*)g1)[t], bv = ((const float4*)b1)[t];
  const float4 kgv = ((const float4*)kg)[t], kbv = ((const float4*)kb)[t];
  const float e0 = u.x * gv.x * kgv.x, e1 = u.y * gv.y * kgv.y;
  const float e2 = u.z * gv.z * kgv.z, e3 = u.w * gv.w * kgv.w;
  C1h[h * 512 + 2 * t] = pkh(e0, e1);
  C1h[h * 512 + 2 * t + 1] = pkh(e2, e3);
  float p2 = u.x * kgv.x * bv.x + u.y * kgv.y * bv.y + u.z * kgv.z * bv.z + u.w * kgv.w * bv.w;
  float p3 = e0 + e1 + e2 + e3;
  float p4 = u.x * kgv.x + u.y * kgv.y + u.z * kgv.z + u.w * kgv.w;
  float p5 = u.x * kbv.x + u.y * kbv.y + u.z * kbv.z + u.w * kbv.w;
  __shared__ float red[4][4];
  p2 = wred_sum(p2); p3 = wred_sum(p3); p4 = wred_sum(p4); p5 = wred_sum(p5);
  const int lane = t & 63, wv = t >> 6;
  if (!lane) { red[wv][0] = p2; red[wv][1] = p3; red[wv][2] = p4; red[wv][3] = p5; }
  __syncthreads();
  if (t < 4) {
    float a = red[0][t] + red[1][t] + red[2][t] + red[3][t];
    hc[t * 16 + h] = a;
  }
}

// ---------- pass 1 over x: fused LN-LN-scores via affine trick ----------
// 16 lanes per ROW-PAIR (2 rows share every LDS read), 8 rows per wave.
__global__ __launch_bounds__(256, 4) void k_scores(
    const float* __restrict__ x, const h2* __restrict__ C1h,
    const h2* __restrict__ g1h, const h2* __restrict__ b1h,
    const float* __restrict__ hc, const float* __restrict__ sconst,
    float* __restrict__ stats, float* __restrict__ sc) {
  __shared__ __align__(16) h2 sC[16 * 512];  // 32 KB  [h][pair]
  __shared__ __align__(16) h2 sG[512], sB[512];
  {
    const uint4* src = (const uint4*)C1h;
    uint4* dst = (uint4*)sC;
    for (int i = threadIdx.x; i < 2048; i += 256) dst[i] = src[i];
    if (threadIdx.x < 128) {
      ((uint4*)sG)[threadIdx.x] = ((const uint4*)g1h)[threadIdx.x];
      ((uint4*)sB)[threadIdx.x] = ((const uint4*)b1h)[threadIdx.x];
    }
  }
  __syncthreads();
  const int lane = threadIdx.x & 63, wv = threadIdx.x >> 6;
  const int g = lane >> 4, j = lane & 15;
  const float c2 = hc[j], c3 = hc[16 + j], c4 = hc[32 + j], c5 = hc[48 + j];
  const float Sg1 = sconst[0], Sb1 = sconst[1], Sbb = sconst[2];
  const float Sgb = sconst[3], Sgg = sconst[4];
  const h2 one = {(_Float16)1.f, (_Float16)1.f};
  const int wid = blockIdx.x * 4 + wv;
#pragma unroll 1
  for (int i = 0; i < 2; i++) {
    const int r0 = wid * 16 + i * 8 + g * 2;  // row pair r0, r0+1
    const float* xr0 = x + (size_t)r0 * D + 8 * j;
    const float* xr1 = xr0 + D;
    float pA[16], pB[16];
#pragma unroll
    for (int h = 0; h < 16; h++) { pA[h] = 0.f; pB[h] = 0.f; }
    float S0a = 0, S1a = 0, Saa = 0, Sba = 0, Sca = 0, Sda = 0;
    float S0b = 0, S1b = 0, Sab = 0, Sbb2 = 0, Scb = 0, Sdb = 0;
#pragma unroll 1
    for (int c = 0; c < 8; c++) {
      const float4 A0 = *(const float4*)(xr0 + 128 * c);
      const float4 B0 = *(const float4*)(xr0 + 128 * c + 4);
      const float4 A1 = *(const float4*)(xr1 + 128 * c);
      const float4 B1 = *(const float4*)(xr1 + 128 * c + 4);
      const h2 xa0 = pkh(A0.x, A0.y), xa1 = pkh(A0.z, A0.w);
      const h2 xa2 = pkh(B0.x, B0.y), xa3 = pkh(B0.z, B0.w);
      const h2 xb0 = pkh(A1.x, A1.y), xb1 = pkh(A1.z, A1.w);
      const h2 xb2 = pkh(B1.x, B1.y), xb3 = pkh(B1.z, B1.w);
      const uint4 gu = ((const uint4*)sG)[16 * c + j];
      const uint4 bu = ((const uint4*)sB)[16 * c + j];
      const h2 g0 = bch(gu.x), g1p = bch(gu.y), g2 = bch(gu.z), g3 = bch(gu.w);
      const h2 b0 = bch(bu.x), b1p = bch(bu.y), b2 = bch(bu.z), b3 = bch(bu.w);
      // row A stats
      S0a = fdot2(xa0, one, S0a); S0a = fdot2(xa1, one, S0a);
      S0a = fdot2(xa2, one, S0a); S0a = fdot2(xa3, one, S0a);
      S1a = fdot2(xa0, xa0, S1a); S1a = fdot2(xa1, xa1, S1a);
      S1a = fdot2(xa2, xa2, S1a); S1a = fdot2(xa3, xa3, S1a);
      Saa = fdot2(g0, xa0, Saa); Saa = fdot2(g1p, xa1, Saa);
      Saa = fdot2(g2, xa2, Saa); Saa = fdot2(g3, xa3, Saa);
      {
        const h2 q0 = g0 * xa0, q1 = g1p * xa1, q2 = g2 * xa2, q3 = g3 * xa3;
        Sba = fdot2(g0, q0, Sba); Sba = fdot2(g1p, q1, Sba);
        Sba = fdot2(g2, q2, Sba); Sba = fdot2(g3, q3, Sba);
        Sca = fdot2(q0, q0, Sca); Sca = fdot2(q1, q1, Sca);
        Sca = fdot2(q2, q2, Sca); Sca = fdot2(q3, q3, Sca);
        Sda = fdot2(b0, q0, Sda); Sda = fdot2(b1p, q1, Sda);
        Sda = fdot2(b2, q2, Sda); Sda = fdot2(b3, q3, Sda);
      }
      // row B stats
      S0b = fdot2(xb0, one, S0b); S0b = fdot2(xb1, one, S0b);
      S0b = fdot2(xb2, one, S0b); S0b = fdot2(xb3, one, S0b);
      S1b = fdot2(xb0, xb0, S1b); S1b = fdot2(xb1, xb1, S1b);
      S1b = fdot2(xb2, xb2, S1b); S1b = fdot2(xb3, xb3, S1b);
      Sab = fdot2(g0, xb0, Sab); Sab = fdot2(g1p, xb1, Sab);
      Sab = fdot2(g2, xb2, Sab); Sab = fdot2(g3, xb3, Sab);
      {
        const h2 q0 = g0 * xb0, q1 = g1p * xb1, q2 = g2 * xb2, q3 = g3 * xb3;
        Sbb2 = fdot2(g0, q0, Sbb2); Sbb2 = fdot2(g1p, q1, Sbb2);
        Sbb2 = fdot2(g2, q2, Sbb2); Sbb2 = fdot2(g3, q3, Sbb2);
        Scb = fdot2(q0, q0, Scb); Scb = fdot2(q1, q1, Scb);
        Scb = fdot2(q2, q2, Scb); Scb = fdot2(q3, q3, Scb);
        Sdb = fdot2(b0, q0, Sdb); Sdb = fdot2(b1p, q1, Sdb);
        Sdb = fdot2(b2, q2, Sdb); Sdb = fdot2(b3, q3, Sdb);
      }
      // head dots: one sC read feeds BOTH rows (8 fdot2 per read)
#pragma unroll
      for (int h = 0; h < 16; h++) {
        const uint4 u = ((const uint4*)sC)[h * 128 + 16 * c + j];
        const h2 u0 = bch(u.x), u1 = bch(u.y), u2 = bch(u.z), u3 = bch(u.w);
        float a0 = pA[h];
        a0 = fdot2(u0, xa0, a0); a0 = fdot2(u1, xa1, a0);
        a0 = fdot2(u2, xa2, a0); a0 = fdot2(u3, xa3, a0);
        pA[h] = a0;
        float a1 = pB[h];
        a1 = fdot2(u0, xb0, a1); a1 = fdot2(u1, xb1, a1);
        a1 = fdot2(u2, xb2, a1); a1 = fdot2(u3, xb3, a1);
        pB[h] = a1;
      }
    }
    // stats butterflies within 16-lane group (both rows)
#pragma unroll
    for (int m = 1; m < 16; m <<= 1) {
      S0a += __shfl_xor(S0a, m, 64); S1a += __shfl_xor(S1a, m, 64);
      Saa += __shfl_xor(Saa, m, 64); Sba += __shfl_xor(Sba, m, 64);
      Sca += __shfl_xor(Sca, m, 64); Sda += __shfl_xor(Sda, m, 64);
      S0b += __shfl_xor(S0b, m, 64); S1b += __shfl_xor(S1b, m, 64);
      Sab += __shfl_xor(Sab, m, 64); Sbb2 += __shfl_xor(Sbb2, m, 64);
      Scb += __shfl_xor(Scb, m, 64); Sdb += __shfl_xor(Sdb, m, 64);
    }
    // transpose-reduce both rows: lane j ends with sum-over-group of p[j]
    float qA, qB;
    {
      float q8[8];
#pragma unroll
      for (int h = 0; h < 8; h++) {
        const float a = pA[2 * h], bb = pA[2 * h + 1];
        const float sent = (j & 1) ? a : bb;
        const float keep = (j & 1) ? bb : a;
        q8[h] = keep + __shfl_xor(sent, 1, 64);
      }
      float q4[4];
#pragma unroll
      for (int h = 0; h < 4; h++) {
        const float a = q8[2 * h], bb = q8[2 * h + 1];
        const float sent = (j & 2) ? a : bb;
        const float keep = (j & 2) ? bb : a;
        q4[h] = keep + __shfl_xor(sent, 2, 64);
      }
      float q2[2];
#pragma unroll
      for (int h = 0; h < 2; h++) {
        const float a = q4[2 * h], bb = q4[2 * h + 1];
        const float sent = (j & 4) ? a : bb;
        const float keep = (j & 4) ? bb : a;
        q2[h] = keep + __shfl_xor(sent, 4, 64);
      }
      const float a = q2[0], bb = q2[1];
      const float sent = (j & 8) ? a : bb;
      const float keep = (j & 8) ? bb : a;
      qA = keep + __shfl_xor(sent, 8, 64);
    }
    {
      float q8[8];
#pragma unroll
      for (int h = 0; h < 8; h++) {
        const float a = pB[2 * h], bb = pB[2 * h + 1];
        const float sent = (j & 1) ? a : bb;
        const float keep = (j & 1) ? bb : a;
        q8[h] = keep + __shfl_xor(sent, 1, 64);
      }
      float q4[4];
#pragma unroll
      for (int h = 0; h < 4; h++) {
        const float a = q8[2 * h], bb = q8[2 * h + 1];
        const float sent = (j & 2) ? a : bb;
        const float keep = (j & 2) ? bb : a;
        q4[h] = keep + __shfl_xor(sent, 2, 64);
      }
      float q2[2];
#pragma unroll
      for (int h = 0; h < 2; h++) {
        const float a = q4[2 * h], bb = q4[2 * h + 1];
        const float sent = (j & 4) ? a : bb;
        const float keep = (j & 4) ? bb : a;
        q2[h] = keep + __shfl_xor(sent, 4, 64);
      }
      const float a = q2[0], bb = q2[1];
      const float sent = (j & 8) ? a : bb;
      const float keep = (j & 8) ? bb : a;
      qB = keep + __shfl_xor(sent, 8, 64);
    }
    // final scalars, row A
    {
      const float m1 = S0a * (1.f / D);
      const float rs1 = rsqrtf(S1a * (1.f / D) - m1 * m1 + EPS_LN);
      const float m2 = (rs1 * (Saa - m1 * Sg1) + Sb1) * (1.f / D);
      const float sxn2 = rs1 * rs1 * Sca + 2.f * rs1 * (Sda - m1 * rs1 * Sba) +
                         (Sbb - 2.f * m1 * rs1 * Sgb + m1 * m1 * rs1 * rs1 * Sgg);
      const float rs2 = rsqrtf(sxn2 * (1.f / D) - m2 * m2 + EPS_LN);
      if (j == 0) ((float4*)stats)[r0] = make_float4(m1, rs1, m2, rs2);
      const float rs12 = rs1 * rs2;
      sc[(size_t)r0 * 16 + j] = rs12 * qA - rs12 * m1 * c3 + rs2 * (c2 - m2 * c4) + c5;
    }
    // final scalars, row B
    {
      const float m1 = S0b * (1.f / D);
      const float rs1 = rsqrtf(S1b * (1.f / D) - m1 * m1 + EPS_LN);
      const float m2 = (rs1 * (Sab - m1 * Sg1) + Sb1) * (1.f / D);
      const float sxn2 = rs1 * rs1 * Scb + 2.f * rs1 * (Sdb - m1 * rs1 * Sbb2) +
                         (Sbb - 2.f * m1 * rs1 * Sgb + m1 * m1 * rs1 * rs1 * Sgg);
      const float rs2 = rsqrtf(sxn2 * (1.f / D) - m2 * m2 + EPS_LN);
      if (j == 0) ((float4*)stats)[r0 + 1] = make_float4(m1, rs1, m2, rs2);
      const float rs12 = rs1 * rs2;
      sc[(size_t)(r0 + 1) * 16 + j] =
          rs12 * qB - rs12 * m1 * c3 + rs2 * (c2 - m2 * c4) + c5;
    }
  }
}

// ---------- softmax stage 1: per-chunk max + sum(exp(v-max)) ----------
__global__ void k_smax1(const float* __restrict__ sc, float* __restrict__ pmax,
                        float* __restrict__ psum) {
  const int blk = blockIdx.x, t = threadIdx.x;
  const int b = blk >> 4, c = blk & 15;
  const int r0 = b * S + c * 512;
  __shared__ float lM[4][16], lS[4][16];
  float mx[16];
#pragma unroll
  for (int h = 0; h < 16; h++) mx[h] = -3.4e38f;
#pragma unroll
  for (int rr = 0; rr < 2; rr++) {
    const float4* row = (const float4*)(sc + (size_t)(r0 + t + 256 * rr) * 16);
    const float4 v0 = row[0], v1 = row[1], v2 = row[2], v3 = row[3];
    mx[0] = fmaxf(mx[0], v0.x); mx[1] = fmaxf(mx[1], v0.y);
    mx[2] = fmaxf(mx[2], v0.z); mx[3] = fmaxf(mx[3], v0.w);
    mx[4] = fmaxf(mx[4], v1.x); mx[5] = fmaxf(mx[5], v1.y);
    mx[6] = fmaxf(mx[6], v1.z); mx[7] = fmaxf(mx[7], v1.w);
    mx[8] = fmaxf(mx[8], v2.x); mx[9] = fmaxf(mx[9], v2.y);
    mx[10] = fmaxf(mx[10], v2.z); mx[11] = fmaxf(mx[11], v2.w);
    mx[12] = fmaxf(mx[12], v3.x); mx[13] = fmaxf(mx[13], v3.y);
    mx[14] = fmaxf(mx[14], v3.z); mx[15] = fmaxf(mx[15], v3.w);
  }
  const int lane = t & 63, wv = t >> 6;
#pragma unroll
  for (int h = 0; h < 16; h++) mx[h] = wred_max(mx[h]);
  if (!lane) {
#pragma unroll
    for (int h = 0; h < 16; h++) lM[wv][h] = mx[h];
  }
  __syncthreads();
  float M[16];
#pragma unroll
  for (int h = 0; h < 16; h++)
    M[h] = fmaxf(fmaxf(lM[0][h], lM[1][h]), fmaxf(lM[2][h], lM[3][h]));
  float sm[16];
#pragma unroll
  for (int h = 0; h < 16; h++) sm[h] = 0.f;
#pragma unroll
  for (int rr = 0; rr < 2; rr++) {
    const float4* row = (const float4*)(sc + (size_t)(r0 + t + 256 * rr) * 16);
    const float4 v0 = row[0], v1 = row[1], v2 = row[2], v3 = row[3];
    sm[0] += __expf(v0.x - M[0]); sm[1] += __expf(v0.y - M[1]);
    sm[2] += __expf(v0.z - M[2]); sm[3] += __expf(v0.w - M[3]);
    sm[4] += __expf(v1.x - M[4]); sm[5] += __expf(v1.y - M[5]);
    sm[6] += __expf(v1.z - M[6]); sm[7] += __expf(v1.w - M[7]);
    sm[8] += __expf(v2.x - M[8]); sm[9] += __expf(v2.y - M[9]);
    sm[10] += __expf(v2.z - M[10]); sm[11] += __expf(v2.w - M[11]);
    sm[12] += __expf(v3.x - M[12]); sm[13] += __expf(v3.y - M[13]);
    sm[14] += __expf(v3.z - M[14]); sm[15] += __expf(v3.w - M[15]);
  }
#pragma unroll
  for (int h = 0; h < 16; h++) sm[h] = wred_sum(sm[h]);
  if (!lane) {
#pragma unroll
    for (int h = 0; h < 16; h++) lS[wv][h] = sm[h];
  }
  __syncthreads();
  if (t < 16) {
    float m = fmaxf(fmaxf(lM[0][t], lM[1][t]), fmaxf(lM[2][t], lM[3][t]));
    float s = lS[0][t] + lS[1][t] + lS[2][t] + lS[3][t];
    pmax[blk * 16 + t] = m;
    psum[blk * 16 + t] = s;
  }
}

// ---------- softmax stage 2: combine 16 chunks per (b,h) ----------
__global__ void k_smax2(const float* __restrict__ pmax, const float* __restrict__ psum,
                        float* __restrict__ gmax, float* __restrict__ ginv) {
  const int t = threadIdx.x;  // 128 = B*H
  const int b = t >> 4, h = t & 15;
  float M = -3.4e38f;
  for (int c = 0; c < 16; c++) M = fmaxf(M, pmax[(b * 16 + c) * 16 + h]);
  float sum = 0.f;
  for (int c = 0; c < 16; c++)
    sum += psum[(b * 16 + c) * 16 + h] * __expf(pmax[(b * 16 + c) * 16 + h] - M);
  gmax[t] = M;
  ginv[t] = 1.f / (sum + 1e-9f);
}

// ---------- softmax stage 3: materialize attn in place ----------
__global__ void k_smax3(float* __restrict__ sc, const float* __restrict__ gmax,
                        const float* __restrict__ ginv) {
  const int r = blockIdx.x * 256 + threadIdx.x;
  const int b = r >> 13;
  float4 M[4], I[4];
#pragma unroll
  for (int k = 0; k < 4; k++) {
    M[k] = ((const float4*)(gmax + b * 16))[k];
    I[k] = ((const float4*)(ginv + b * 16))[k];
  }
  float4* row = (float4*)(sc + (size_t)r * 16);
#pragma unroll
  for (int k = 0; k < 4; k++) {
    float4 v = row[k];
    v.x = fminf(fmaxf(__expf(v.x - M[k].x) * I[k].x, 1e-9f), 1.f);
    v.y = fminf(fmaxf(__expf(v.y - M[k].y) * I[k].y, 1e-9f), 1.f);
    v.z = fminf(fmaxf(__expf(v.z - M[k].z) * I[k].z, 1e-9f), 1.f);
    v.w = fminf(fmaxf(__expf(v.w - M[k].w) * I[k].w, 1e-9f), 1.f);
    row[k] = v;
  }
}

// ---------- pass 2 over x: vn recompute + attn-weighted column accumulate ----------
__global__ __launch_bounds__(512) void k_accv(
    const float* __restrict__ x, const float* __restrict__ stats,
    const float* __restrict__ attn,
    const float* __restrict__ g1, const float* __restrict__ b1,
    const float* __restrict__ vg, const float* __restrict__ vb,
    float* __restrict__ part, int CH, int RPC) {
  const int b = blockIdx.x / CH, ch = blockIdx.x % CH;
  const int c0 = threadIdx.x * 2;
  const float2 gv = *(const float2*)(g1 + c0), bv = *(const float2*)(b1 + c0);
  const float2 vgv = *(const float2*)(vg + c0), vbv = *(const float2*)(vb + c0);
  float acc0[16], acc1[16];
#pragma unroll
  for (int h = 0; h < 16; h++) { acc0[h] = 0.f; acc1[h] = 0.f; }
  const int r0 = b * S + ch * RPC;
#pragma unroll 2
  for (int i = 0; i < RPC; i++) {
    const int r = r0 + i;
    const float4 st = ((const float4*)stats)[r];  // m1 rs1 m2 rs2
    const float2 xv = *(const float2*)(x + (size_t)r * D + c0);
    const float4* wr = (const float4*)(attn + (size_t)r * 16);
    const float4 w0 = wr[0], w1 = wr[1], w2 = wr[2], w3 = wr[3];
    float xn0 = (xv.x - st.x) * st.y * gv.x + bv.x;
    float xn1 = (xv.y - st.x) * st.y * gv.y + bv.y;
    const float v0 = (xn0 - st.z) * st.w * vgv.x + vbv.x;
    const float v1 = (xn1 - st.z) * st.w * vgv.y + vbv.y;
    acc0[0] = fmaf(w0.x, v0, acc0[0]);   acc1[0] = fmaf(w0.x, v1, acc1[0]);
    acc0[1] = fmaf(w0.y, v0, acc0[1]);   acc1[1] = fmaf(w0.y, v1, acc1[1]);
    acc0[2] = fmaf(w0.z, v0, acc0[2]);   acc1[2] = fmaf(w0.z, v1, acc1[2]);
    acc0[3] = fmaf(w0.w, v0, acc0[3]);   acc1[3] = fmaf(w0.w, v1, acc1[3]);
    acc0[4] = fmaf(w1.x, v0, acc0[4]);   acc1[4] = fmaf(w1.x, v1, acc1[4]);
    acc0[5] = fmaf(w1.y, v0, acc0[5]);   acc1[5] = fmaf(w1.y, v1, acc1[5]);
    acc0[6] = fmaf(w1.z, v0, acc0[6]);   acc1[6] = fmaf(w1.z, v1, acc1[6]);
    acc0[7] = fmaf(w1.w, v0, acc0[7]);   acc1[7] = fmaf(w1.w, v1, acc1[7]);
    acc0[8] = fmaf(w2.x, v0, acc0[8]);   acc1[8] = fmaf(w2.x, v1, acc1[8]);
    acc0[9] = fmaf(w2.y, v0, acc0[9]);   acc1[9] = fmaf(w2.y, v1, acc1[9]);
    acc0[10] = fmaf(w2.z, v0, acc0[10]); acc1[10] = fmaf(w2.z, v1, acc1[10]);
    acc0[11] = fmaf(w2.w, v0, acc0[11]); acc1[11] = fmaf(w2.w, v1, acc1[11]);
    acc0[12] = fmaf(w3.x, v0, acc0[12]); acc1[12] = fmaf(w3.x, v1, acc1[12]);
    acc0[13] = fmaf(w3.y, v0, acc0[13]); acc1[13] = fmaf(w3.y, v1, acc1[13]);
    acc0[14] = fmaf(w3.z, v0, acc0[14]); acc1[14] = fmaf(w3.z, v1, acc1[14]);
    acc0[15] = fmaf(w3.w, v0, acc0[15]); acc1[15] = fmaf(w3.w, v1, acc1[15]);
  }
  float* po = part + (size_t)blockIdx.x * (H * D);
#pragma unroll
  for (int h = 0; h < 16; h++)
    *(float2*)(po + h * D + c0) = make_float2(acc0[h], acc1[h]);
}

// ---------- reduce chunk partials -> wsum[b][h][d] ----------
__global__ void k_redpart(const float* __restrict__ part, float* __restrict__ wsum,
                          int CH) {
  const int b = blockIdx.x >> 4, h = blockIdx.x & 15;
  const int d = threadIdx.x * 4;
  float4 a = make_float4(0.f, 0.f, 0.f, 0.f);
  for (int k = 0; k < CH; k++) {
    const float4 p = *(const float4*)(part + ((size_t)(b * CH + k) * H + h) * D + d);
    a.x += p.x; a.y += p.y; a.z += p.z; a.w += p.w;
  }
  *(float4*)(wsum + ((size_t)b * H + h) * D + d) = a;
}

// ---------- out[b][j] = W[j,:] . src[b, (maybe head-sliced)] + bias[j] ----------
__global__ void k_proj8(const float* __restrict__ src, const float* __restrict__ W,
                        const float* __restrict__ bias, float* __restrict__ out,
                        int bstride, int hstride) {
  const int j = blockIdx.x, lane = threadIdx.x;
  const int h = j >> 6;
  const float4* wr = (const float4*)(W + (size_t)j * D);
  float acc[8];
#pragma unroll
  for (int b = 0; b < 8; b++) acc[b] = 0.f;
#pragma unroll
  for (int k = 0; k < 4; k++) {
    const float4 w4 = wr[lane + 64 * k];
#pragma unroll
    for (int b = 0; b < 8; b++) {
      const float4 s4 =
          ((const float4*)(src + (size_t)b * bstride + (size_t)h * hstride))[lane + 64 * k];
      acc[b] = fmaf(w4.x, s4.x, acc[b]); acc[b] = fmaf(w4.y, s4.y, acc[b]);
      acc[b] = fmaf(w4.z, s4.z, acc[b]); acc[b] = fmaf(w4.w, s4.w, acc[b]);
    }
  }
#pragma unroll
  for (int b = 0; b < 8; b++) acc[b] = wred_sum(acc[b]);
  if (!lane) {
    const float bj = bias[j];
#pragma unroll
    for (int b = 0; b < 8; b++) out[(size_t)b * D + j] = acc[b] + bj;
  }
}

extern "C" void kernel_launch(void* const* d_in, const int* in_sizes, int n_in,
                              void* d_out, int out_size, void* d_ws, size_t ws_size,
                              hipStream_t stream) {
  const float* x = (const float*)d_in[0];
  const float* query = (const float*)d_in[1];
  const float* norm_g = (const float*)d_in[2];
  const float* norm_b = (const float*)d_in[3];
  const float* nq_g = (const float*)d_in[4];
  const float* nq_b = (const float*)d_in[5];
  const float* nk_g = (const float*)d_in[6];
  const float* nk_b = (const float*)d_in[7];
  const float* nv_g = (const float*)d_in[8];
  const float* nv_b = (const float*)d_in[9];
  const float* no_g = (const float*)d_in[10];
  const float* no_b = (const float*)d_in[11];
  const float* Wq = (const float*)d_in[12];
  const float* bq = (const float*)d_in[13];
  const float* Wk = (const float*)d_in[14];
  // d_in[15] = bk: constant per (b,h) in scores -> cancels in softmax
  const float* Wv = (const float*)d_in[16];
  const float* bv = (const float*)d_in[17];
  const float* Wo = (const float*)d_in[18];
  const float* bo = (const float*)d_in[19];

  char* ws = (char*)d_ws;
  float* qn = (float*)(ws + 0);
  float* qv = (float*)(ws + 4096);
  float* Uf = (float*)(ws + 8192);
  h2* C1h = (h2*)(ws + 73728);
  h2* g1h = (h2*)(ws + 106496);
  h2* b1h = (h2*)(ws + 108544);
  float* hc = (float*)(ws + 110592);
  float* sconst = (float*)(ws + 110848);
  float* gmax = (float*)(ws + 110912);
  float* ginv = (float*)(ws + 111424);
  float* pmax = (float*)(ws + 111936);
  float* psum = (float*)(ws + 120128);
  float* stats = (float*)(ws + 128320);
  float* sc = (float*)(ws + 1176896);
  float* wsum = (float*)(ws + 5371200);
  float* av = (float*)(ws + 5895488);
  float* yb = (float*)(ws + 5928256);
  float* part = (float*)(ws + 5961024);

  int CH = 64;
  while (CH > 1 && 5961024ull + (size_t)B * CH * H * D * 4 > ws_size) CH >>= 1;
  const int RPC = S / CH;

  k_ln256<<<1, 256, 0, stream>>>(query, nq_g, nq_b, qn);
  k_qproj<<<256, 256, 0, stream>>>(qn, Wq, bq, qv);
  k_uproj<<<64, 256, 0, stream>>>(qv, Wk, Uf);
  k_prep0<<<1, 256, 0, stream>>>(norm_g, norm_b, g1h, b1h, sconst);
  k_prep1<<<16, 256, 0, stream>>>(Uf, norm_g, norm_b, nk_g, nk_b, C1h, hc);
  k_scores<<<1024, 256, 0, stream>>>(x, C1h, g1h, b1h, hc, sconst, stats, sc);
  k_smax1<<<128, 256, 0, stream>>>(sc, pmax, psum);
  k_smax2<<<1, 128, 0, stream>>>(pmax, psum, gmax, ginv);
  k_smax3<<<256, 256, 0, stream>>>(sc, gmax, ginv);
  k_accv<<<B * CH, 512, 0, stream>>>(x, stats, sc, norm_g, norm_b, nv_g, nv_b, part,
                                     CH, RPC);
  k_redpart<<<128, 256, 0, stream>>>(part, wsum, CH);
  k_proj8<<<1024, 64, 0, stream>>>(wsum, Wv, bv, av, H * D, D);  // V-proj on pooled
  k_proj8<<<1024, 64, 0, stream>>>(av, Wo, bo, yb, D, 0);        // O-proj
  k_ln256<<<8, 256, 0, stream>>>(yb, no_g, no_b, (float*)d_out);
}

// Round 9
// 180.018 us; speedup vs baseline: 2.8639x; 1.0009x over previous
//
#include <hip/hip_runtime.h>
#include <math.h>

#define D 1024
#define S 8192
#define B 8
#define H 16
#define NROWS (B * S)
#define EPS_LN 1e-5f

typedef _Float16 h2 __attribute__((ext_vector_type(2)));

__device__ __forceinline__ float wred_sum(float v) {
#pragma unroll
  for (int m = 1; m < 64; m <<= 1) v += __shfl_xor(v, m, 64);
  return v;
}
__device__ __forceinline__ float wred_max(float v) {
#pragma unroll
  for (int m = 1; m < 64; m <<= 1) v = fmaxf(v, __shfl_xor(v, m, 64));
  return v;
}
__device__ __forceinline__ h2 pkh(float a, float b) {
#if __has_builtin(__builtin_amdgcn_cvt_pkrtz)
  return __builtin_bit_cast(h2, __builtin_amdgcn_cvt_pkrtz(a, b));
#else
  h2 r; r.x = (_Float16)a; r.y = (_Float16)b; return r;
#endif
}
__device__ __forceinline__ float fdot2(h2 a, h2 b, float c) {
#if __has_builtin(__builtin_amdgcn_fdot2)
  typedef __fp16 fp16v2 __attribute__((ext_vector_type(2)));
  return __builtin_amdgcn_fdot2(__builtin_bit_cast(fp16v2, a),
                                __builtin_bit_cast(fp16v2, b), c, false);
#else
  return c + (float)a.x * (float)b.x + (float)a.y * (float)b.y;
#endif
}
__device__ __forceinline__ h2 bch(unsigned int u) { return __builtin_bit_cast(h2, u); }

// ---------- LN over one 1024-row per block (256 thr) ----------
__global__ void k_ln256(const float* __restrict__ in, const float* __restrict__ g,
                        const float* __restrict__ bb, float* __restrict__ out) {
  const int b = blockIdx.x, t = threadIdx.x;
  float4 v = ((const float4*)(in + (size_t)b * D))[t];
  float s = v.x + v.y + v.z + v.w;
  float s2 = fmaf(v.x, v.x, fmaf(v.y, v.y, fmaf(v.z, v.z, v.w * v.w)));
  __shared__ float red[8];
  float ws = wred_sum(s), ws2 = wred_sum(s2);
  const int lane = t & 63, wv = t >> 6;
  if (!lane) { red[wv] = ws; red[wv + 4] = ws2; }
  __syncthreads();
  ws = red[0] + red[1] + red[2] + red[3];
  ws2 = red[4] + red[5] + red[6] + red[7];
  const float m = ws * (1.f / D);
  const float rs = rsqrtf(ws2 * (1.f / D) - m * m + EPS_LN);
  const float4 gg = ((const float4*)g)[t], bv = ((const float4*)bb)[t];
  float4 o;
  o.x = (v.x - m) * rs * gg.x + bv.x;
  o.y = (v.y - m) * rs * gg.y + bv.y;
  o.z = (v.z - m) * rs * gg.z + bv.z;
  o.w = (v.w - m) * rs * gg.w + bv.w;
  ((float4*)(out + (size_t)b * D))[t] = o;
}

// ---------- q[j] = qn . Wq[j,:] + bq[j] : one wave per j ----------
__global__ void k_qproj(const float* __restrict__ qn, const float* __restrict__ Wq,
                        const float* __restrict__ bq, float* __restrict__ q) {
  const int wv = threadIdx.x >> 6, lane = threadIdx.x & 63;
  const int j = blockIdx.x * 4 + wv;
  const float4* wr = (const float4*)(Wq + (size_t)j * D);
  const float4* qr = (const float4*)qn;
  float acc = 0.f;
#pragma unroll
  for (int k = 0; k < 4; k++) {
    float4 a = qr[lane + 64 * k], w = wr[lane + 64 * k];
    acc = fmaf(a.x, w.x, acc); acc = fmaf(a.y, w.y, acc);
    acc = fmaf(a.z, w.z, acc); acc = fmaf(a.w, w.w, acc);
  }
  acc = wred_sum(acc);
  if (!lane) q[j] = acc + bq[j];
}

// ---------- Uf[h][d] = scale * sum_e q[h*64+e] * Wk[h*64+e][d] (fp32) ----------
__global__ void k_uproj(const float* __restrict__ q, const float* __restrict__ Wk,
                        float* __restrict__ Uf) {
  const int idx = blockIdx.x * 256 + threadIdx.x;
  const int h = idx >> 10, d = idx & (D - 1);
  float acc = 0.f;
#pragma unroll 4
  for (int e = 0; e < 64; e++)
    acc = fmaf(q[h * 64 + e], Wk[(size_t)(h * 64 + e) * D + d], acc);
  Uf[idx] = acc * 0.125f;  // 1/sqrt(64)
}

// ---------- prep0: f16 packs of g1/b1 + 5 weight scalars ----------
__global__ void k_prep0(const float* __restrict__ g, const float* __restrict__ b,
                        h2* __restrict__ g1h, h2* __restrict__ b1h,
                        float* __restrict__ sconst) {
  const int t = threadIdx.x;
  float4 gv = ((const float4*)g)[t], bv = ((const float4*)b)[t];
  g1h[2 * t] = pkh(gv.x, gv.y); g1h[2 * t + 1] = pkh(gv.z, gv.w);
  b1h[2 * t] = pkh(bv.x, bv.y); b1h[2 * t + 1] = pkh(bv.z, bv.w);
  float sg = gv.x + gv.y + gv.z + gv.w;
  float sb = bv.x + bv.y + bv.z + bv.w;
  float sbb = bv.x * bv.x + bv.y * bv.y + bv.z * bv.z + bv.w * bv.w;
  float sgb = gv.x * bv.x + gv.y * bv.y + gv.z * bv.z + gv.w * bv.w;
  float sgg = gv.x * gv.x + gv.y * gv.y + gv.z * gv.z + gv.w * gv.w;
  __shared__ float red[4][5];
  sg = wred_sum(sg); sb = wred_sum(sb); sbb = wred_sum(sbb);
  sgb = wred_sum(sgb); sgg = wred_sum(sgg);
  const int lane = t & 63, wv = t >> 6;
  if (!lane) { red[wv][0] = sg; red[wv][1] = sb; red[wv][2] = sbb; red[wv][3] = sgb; red[wv][4] = sgg; }
  __syncthreads();
  if (t < 5) {
    float a = red[0][t] + red[1][t] + red[2][t] + red[3][t];
    sconst[t] = a;
  }
}

// ---------- prep1: C1h = f16(U*g1*kg) + per-head consts c2..c5 ----------
__global__ void k_prep1(const float* __restrict__ Uf, const float* __restrict__ g1,
                        const float* __restrict__ b1, const float* __restrict__ kg,
                        const float* __restrict__ kb, h2* __restrict__ C1h,
                        float* __restrict__ hc) {
  const int h = blockIdx.x, t = threadIdx.x;
  const float4 u = ((const float4*)(Uf + (size_t)h * D))[t];
  const float4 gv = ((const float4*)g1)[t], bv = ((const float4*)b1)[t];
  const float4 kgv = ((const float4*)kg)[t], kbv = ((const float4*)kb)[t];
  const float e0 = u.x * gv.x * kgv.x, e1 = u.y * gv.y * kgv.y;
  const float e2 = u.z * gv.z * kgv.z, e3 = u.w * gv.w * kgv.w;
  C1h[h * 512 + 2 * t] = pkh(e0, e1);
  C1h[h * 512 + 2 * t + 1] = pkh(e2, e3);
  float p2 = u.x * kgv.x * bv.x + u.y * kgv.y * bv.y + u.z * kgv.z * bv.z + u.w * kgv.w * bv.w;
  float p3 = e0 + e1 + e2 + e3;
  float p4 = u.x * kgv.x + u.y * kgv.y + u.z * kgv.z + u.w * kgv.w;
  float p5 = u.x * kbv.x + u.y * kbv.y + u.z * kbv.z + u.w * kbv.w;
  __shared__ float red[4][4];
  p2 = wred_sum(p2); p3 = wred_sum(p3); p4 = wred_sum(p4); p5 = wred_sum(p5);
  const int lane = t & 63, wv = t >> 6;
  if (!lane) { red[wv][0] = p2; red[wv][1] = p3; red[wv][2] = p4; red[wv][3] = p5; }
  __syncthreads();
  if (t < 4) {
    float a = red[0][t] + red[1][t] + red[2][t] + red[3][t];
    hc[t * 16 + h] = a;
  }
}

// ---------- pass 1 over x: fused LN-LN-scores via affine trick ----------
// 16 lanes per ROW-PAIR; explicit register double-buffer of x loads (latency hiding)
__global__ __launch_bounds__(256, 4) void k_scores(
    const float* __restrict__ x, const h2* __restrict__ C1h,
    const h2* __restrict__ g1h, const h2* __restrict__ b1h,
    const float* __restrict__ hc, const float* __restrict__ sconst,
    float* __restrict__ stats, float* __restrict__ sc) {
  __shared__ __align__(16) h2 sC[16 * 512];  // 32 KB  [h][pair]
  __shared__ __align__(16) h2 sG[512], sB[512];
  {
    const uint4* src = (const uint4*)C1h;
    uint4* dst = (uint4*)sC;
    for (int i = threadIdx.x; i < 2048; i += 256) dst[i] = src[i];
    if (threadIdx.x < 128) {
      ((uint4*)sG)[threadIdx.x] = ((const uint4*)g1h)[threadIdx.x];
      ((uint4*)sB)[threadIdx.x] = ((const uint4*)b1h)[threadIdx.x];
    }
  }
  __syncthreads();
  const int lane = threadIdx.x & 63, wv = threadIdx.x >> 6;
  const int g = lane >> 4, j = lane & 15;
  const float c2 = hc[j], c3 = hc[16 + j], c4 = hc[32 + j], c5 = hc[48 + j];
  const float Sg1 = sconst[0], Sb1 = sconst[1], Sbb = sconst[2];
  const float Sgb = sconst[3], Sgg = sconst[4];
  const h2 one = {(_Float16)1.f, (_Float16)1.f};
  const int wid = blockIdx.x * 4 + wv;
#pragma unroll 1
  for (int i = 0; i < 2; i++) {
    const int r0 = wid * 16 + i * 8 + g * 2;  // row pair r0, r0+1
    const float* xr0 = x + (size_t)r0 * D + 8 * j;
    const float* xr1 = xr0 + D;
    float pA[16], pB[16];
#pragma unroll
    for (int h = 0; h < 16; h++) { pA[h] = 0.f; pB[h] = 0.f; }
    float S0a = 0, S1a = 0, Saa = 0, Sba = 0, Sca = 0, Sda = 0;
    float S0b = 0, S1b = 0, Sab = 0, Sbb2 = 0, Scb = 0, Sdb = 0;
    // prologue: issue chunk 0 loads
    float4 A0 = *(const float4*)(xr0);
    float4 B0 = *(const float4*)(xr0 + 4);
    float4 A1 = *(const float4*)(xr1);
    float4 B1 = *(const float4*)(xr1 + 4);
#pragma unroll 1
    for (int c = 0; c < 8; c++) {
      // prefetch next chunk (clamped; uniform address, no divergence)
      const int cn = (c < 7) ? c + 1 : 7;
      const float4 nA0 = *(const float4*)(xr0 + 128 * cn);
      const float4 nB0 = *(const float4*)(xr0 + 128 * cn + 4);
      const float4 nA1 = *(const float4*)(xr1 + 128 * cn);
      const float4 nB1 = *(const float4*)(xr1 + 128 * cn + 4);
      const h2 xa0 = pkh(A0.x, A0.y), xa1 = pkh(A0.z, A0.w);
      const h2 xa2 = pkh(B0.x, B0.y), xa3 = pkh(B0.z, B0.w);
      const h2 xb0 = pkh(A1.x, A1.y), xb1 = pkh(A1.z, A1.w);
      const h2 xb2 = pkh(B1.x, B1.y), xb3 = pkh(B1.z, B1.w);
      const uint4 gu = ((const uint4*)sG)[16 * c + j];
      const uint4 bu = ((const uint4*)sB)[16 * c + j];
      const h2 g0 = bch(gu.x), g1p = bch(gu.y), g2 = bch(gu.z), g3 = bch(gu.w);
      const h2 b0 = bch(bu.x), b1p = bch(bu.y), b2 = bch(bu.z), b3 = bch(bu.w);
      // row A stats
      S0a = fdot2(xa0, one, S0a); S0a = fdot2(xa1, one, S0a);
      S0a = fdot2(xa2, one, S0a); S0a = fdot2(xa3, one, S0a);
      S1a = fdot2(xa0, xa0, S1a); S1a = fdot2(xa1, xa1, S1a);
      S1a = fdot2(xa2, xa2, S1a); S1a = fdot2(xa3, xa3, S1a);
      Saa = fdot2(g0, xa0, Saa); Saa = fdot2(g1p, xa1, Saa);
      Saa = fdot2(g2, xa2, Saa); Saa = fdot2(g3, xa3, Saa);
      {
        const h2 q0 = g0 * xa0, q1 = g1p * xa1, q2 = g2 * xa2, q3 = g3 * xa3;
        Sba = fdot2(g0, q0, Sba); Sba = fdot2(g1p, q1, Sba);
        Sba = fdot2(g2, q2, Sba); Sba = fdot2(g3, q3, Sba);
        Sca = fdot2(q0, q0, Sca); Sca = fdot2(q1, q1, Sca);
        Sca = fdot2(q2, q2, Sca); Sca = fdot2(q3, q3, Sca);
        Sda = fdot2(b0, q0, Sda); Sda = fdot2(b1p, q1, Sda);
        Sda = fdot2(b2, q2, Sda); Sda = fdot2(b3, q3, Sda);
      }
      // row B stats
      S0b = fdot2(xb0, one, S0b); S0b = fdot2(xb1, one, S0b);
      S0b = fdot2(xb2, one, S0b); S0b = fdot2(xb3, one, S0b);
      S1b = fdot2(xb0, xb0, S1b); S1b = fdot2(xb1, xb1, S1b);
      S1b = fdot2(xb2, xb2, S1b); S1b = fdot2(xb3, xb3, S1b);
      Sab = fdot2(g0, xb0, Sab); Sab = fdot2(g1p, xb1, Sab);
      Sab = fdot2(g2, xb2, Sab); Sab = fdot2(g3, xb3, Sab);
      {
        const h2 q0 = g0 * xb0, q1 = g1p * xb1, q2 = g2 * xb2, q3 = g3 * xb3;
        Sbb2 = fdot2(g0, q0, Sbb2); Sbb2 = fdot2(g1p, q1, Sbb2);
        Sbb2 = fdot2(g2, q2, Sbb2); Sbb2 = fdot2(g3, q3, Sbb2);
        Scb = fdot2(q0, q0, Scb); Scb = fdot2(q1, q1, Scb);
        Scb = fdot2(q2, q2, Scb); Scb = fdot2(q3, q3, Scb);
        Sdb = fdot2(b0, q0, Sdb); Sdb = fdot2(b1p, q1, Sdb);
        Sdb = fdot2(b2, q2, Sdb); Sdb = fdot2(b3, q3, Sdb);
      }
      // head dots: one sC read feeds BOTH rows (8 fdot2 per read)
#pragma unroll
      for (int h = 0; h < 16; h++) {
        const uint4 u = ((const uint4*)sC)[h * 128 + 16 * c + j];
        const h2 u0 = bch(u.x), u1 = bch(u.y), u2 = bch(u.z), u3 = bch(u.w);
        float a0 = pA[h];
        a0 = fdot2(u0, xa0, a0); a0 = fdot2(u1, xa1, a0);
        a0 = fdot2(u2, xa2, a0); a0 = fdot2(u3, xa3, a0);
        pA[h] = a0;
        float a1 = pB[h];
        a1 = fdot2(u0, xb0, a1); a1 = fdot2(u1, xb1, a1);
        a1 = fdot2(u2, xb2, a1); a1 = fdot2(u3, xb3, a1);
        pB[h] = a1;
      }
      A0 = nA0; B0 = nB0; A1 = nA1; B1 = nB1;
    }
    // stats butterflies within 16-lane group (both rows)
#pragma unroll
    for (int m = 1; m < 16; m <<= 1) {
      S0a += __shfl_xor(S0a, m, 64); S1a += __shfl_xor(S1a, m, 64);
      Saa += __shfl_xor(Saa, m, 64); Sba += __shfl_xor(Sba, m, 64);
      Sca += __shfl_xor(Sca, m, 64); Sda += __shfl_xor(Sda, m, 64);
      S0b += __shfl_xor(S0b, m, 64); S1b += __shfl_xor(S1b, m, 64);
      Sab += __shfl_xor(Sab, m, 64); Sbb2 += __shfl_xor(Sbb2, m, 64);
      Scb += __shfl_xor(Scb, m, 64); Sdb += __shfl_xor(Sdb, m, 64);
    }
    // transpose-reduce both rows: lane j ends with sum-over-group of p[j]
    float qA, qB;
    {
      float q8[8];
#pragma unroll
      for (int h = 0; h < 8; h++) {
        const float a = pA[2 * h], bb = pA[2 * h + 1];
        const float sent = (j & 1) ? a : bb;
        const float keep = (j & 1) ? bb : a;
        q8[h] = keep + __shfl_xor(sent, 1, 64);
      }
      float q4[4];
#pragma unroll
      for (int h = 0; h < 4; h++) {
        const float a = q8[2 * h], bb = q8[2 * h + 1];
        const float sent = (j & 2) ? a : bb;
        const float keep = (j & 2) ? bb : a;
        q4[h] = keep + __shfl_xor(sent, 2, 64);
      }
      float q2[2];
#pragma unroll
      for (int h = 0; h < 2; h++) {
        const float a = q4[2 * h], bb = q4[2 * h + 1];
        const float sent = (j & 4) ? a : bb;
        const float keep = (j & 4) ? bb : a;
        q2[h] = keep + __shfl_xor(sent, 4, 64);
      }
      const float a = q2[0], bb = q2[1];
      const float sent = (j & 8) ? a : bb;
      const float keep = (j & 8) ? bb : a;
      qA = keep + __shfl_xor(sent, 8, 64);
    }
    {
      float q8[8];
#pragma unroll
      for (int h = 0; h < 8; h++) {
        const float a = pB[2 * h], bb = pB[2 * h + 1];
        const float sent = (j & 1) ? a : bb;
        const float keep = (j & 1) ? bb : a;
        q8[h] = keep + __shfl_xor(sent, 1, 64);
      }
      float q4[4];
#pragma unroll
      for (int h = 0; h < 4; h++) {
        const float a = q8[2 * h], bb = q8[2 * h + 1];
        const float sent = (j & 2) ? a : bb;
        const float keep = (j & 2) ? bb : a;
        q4[h] = keep + __shfl_xor(sent, 2, 64);
      }
      float q2[2];
#pragma unroll
      for (int h = 0; h < 2; h++) {
        const float a = q4[2 * h], bb = q4[2 * h + 1];
        const float sent = (j & 4) ? a : bb;
        const float keep = (j & 4) ? bb : a;
        q2[h] = keep + __shfl_xor(sent, 4, 64);
      }
      const float a = q2[0], bb = q2[1];
      const float sent = (j & 8) ? a : bb;
      const float keep = (j & 8) ? bb : a;
      qB = keep + __shfl_xor(sent, 8, 64);
    }
    // final scalars, row A
    {
      const float m1 = S0a * (1.f / D);
      const float rs1 = rsqrtf(S1a * (1.f / D) - m1 * m1 + EPS_LN);
      const float m2 = (rs1 * (Saa - m1 * Sg1) + Sb1) * (1.f / D);
      const float sxn2 = rs1 * rs1 * Sca + 2.f * rs1 * (Sda - m1 * rs1 * Sba) +
                         (Sbb - 2.f * m1 * rs1 * Sgb + m1 * m1 * rs1 * rs1 * Sgg);
      const float rs2 = rsqrtf(sxn2 * (1.f / D) - m2 * m2 + EPS_LN);
      if (j == 0) ((float4*)stats)[r0] = make_float4(m1, rs1, m2, rs2);
      const float rs12 = rs1 * rs2;
      sc[(size_t)r0 * 16 + j] = rs12 * qA - rs12 * m1 * c3 + rs2 * (c2 - m2 * c4) + c5;
    }
    // final scalars, row B
    {
      const float m1 = S0b * (1.f / D);
      const float rs1 = rsqrtf(S1b * (1.f / D) - m1 * m1 + EPS_LN);
      const float m2 = (rs1 * (Sab - m1 * Sg1) + Sb1) * (1.f / D);
      const float sxn2 = rs1 * rs1 * Scb + 2.f * rs1 * (Sdb - m1 * rs1 * Sbb2) +
                         (Sbb - 2.f * m1 * rs1 * Sgb + m1 * m1 * rs1 * rs1 * Sgg);
      const float rs2 = rsqrtf(sxn2 * (1.f / D) - m2 * m2 + EPS_LN);
      if (j == 0) ((float4*)stats)[r0 + 1] = make_float4(m1, rs1, m2, rs2);
      const float rs12 = rs1 * rs2;
      sc[(size_t)(r0 + 1) * 16 + j] =
          rs12 * qB - rs12 * m1 * c3 + rs2 * (c2 - m2 * c4) + c5;
    }
  }
}

// ---------- softmax stage 1: per-chunk max + sum(exp(v-max)) ----------
__global__ void k_smax1(const float* __restrict__ sc, float* __restrict__ pmax,
                        float* __restrict__ psum) {
  const int blk = blockIdx.x, t = threadIdx.x;
  const int b = blk >> 4, c = blk & 15;
  const int r0 = b * S + c * 512;
  __shared__ float lM[4][16], lS[4][16];
  float mx[16];
#pragma unroll
  for (int h = 0; h < 16; h++) mx[h] = -3.4e38f;
#pragma unroll
  for (int rr = 0; rr < 2; rr++) {
    const float4* row = (const float4*)(sc + (size_t)(r0 + t + 256 * rr) * 16);
    const float4 v0 = row[0], v1 = row[1], v2 = row[2], v3 = row[3];
    mx[0] = fmaxf(mx[0], v0.x); mx[1] = fmaxf(mx[1], v0.y);
    mx[2] = fmaxf(mx[2], v0.z); mx[3] = fmaxf(mx[3], v0.w);
    mx[4] = fmaxf(mx[4], v1.x); mx[5] = fmaxf(mx[5], v1.y);
    mx[6] = fmaxf(mx[6], v1.z); mx[7] = fmaxf(mx[7], v1.w);
    mx[8] = fmaxf(mx[8], v2.x); mx[9] = fmaxf(mx[9], v2.y);
    mx[10] = fmaxf(mx[10], v2.z); mx[11] = fmaxf(mx[11], v2.w);
    mx[12] = fmaxf(mx[12], v3.x); mx[13] = fmaxf(mx[13], v3.y);
    mx[14] = fmaxf(mx[14], v3.z); mx[15] = fmaxf(mx[15], v3.w);
  }
  const int lane = t & 63, wv = t >> 6;
#pragma unroll
  for (int h = 0; h < 16; h++) mx[h] = wred_max(mx[h]);
  if (!lane) {
#pragma unroll
    for (int h = 0; h < 16; h++) lM[wv][h] = mx[h];
  }
  __syncthreads();
  float M[16];
#pragma unroll
  for (int h = 0; h < 16; h++)
    M[h] = fmaxf(fmaxf(lM[0][h], lM[1][h]), fmaxf(lM[2][h], lM[3][h]));
  float sm[16];
#pragma unroll
  for (int h = 0; h < 16; h++) sm[h] = 0.f;
#pragma unroll
  for (int rr = 0; rr < 2; rr++) {
    const float4* row = (const float4*)(sc + (size_t)(r0 + t + 256 * rr) * 16);
    const float4 v0 = row[0], v1 = row[1], v2 = row[2], v3 = row[3];
    sm[0] += __expf(v0.x - M[0]); sm[1] += __expf(v0.y - M[1]);
    sm[2] += __expf(v0.z - M[2]); sm[3] += __expf(v0.w - M[3]);
    sm[4] += __expf(v1.x - M[4]); sm[5] += __expf(v1.y - M[5]);
    sm[6] += __expf(v1.z - M[6]); sm[7] += __expf(v1.w - M[7]);
    sm[8] += __expf(v2.x - M[8]); sm[9] += __expf(v2.y - M[9]);
    sm[10] += __expf(v2.z - M[10]); sm[11] += __expf(v2.w - M[11]);
    sm[12] += __expf(v3.x - M[12]); sm[13] += __expf(v3.y - M[13]);
    sm[14] += __expf(v3.z - M[14]); sm[15] += __expf(v3.w - M[15]);
  }
#pragma unroll
  for (int h = 0; h < 16; h++) sm[h] = wred_sum(sm[h]);
  if (!lane) {
#pragma unroll
    for (int h = 0; h < 16; h++) lS[wv][h] = sm[h];
  }
  __syncthreads();
  if (t < 16) {
    float m = fmaxf(fmaxf(lM[0][t], lM[1][t]), fmaxf(lM[2][t], lM[3][t]));
    float s = lS[0][t] + lS[1][t] + lS[2][t] + lS[3][t];
    pmax[blk * 16 + t] = m;
    psum[blk * 16 + t] = s;
  }
}

// ---------- softmax stage 2: combine 16 chunks per (b,h) ----------
__global__ void k_smax2(const float* __restrict__ pmax, const float* __restrict__ psum,
                        float* __restrict__ gmax, float* __restrict__ ginv) {
  const int t = threadIdx.x;  // 128 = B*H
  const int b = t >> 4, h = t & 15;
  float M = -3.4e38f;
  for (int c = 0; c < 16; c++) M = fmaxf(M, pmax[(b * 16 + c) * 16 + h]);
  float sum = 0.f;
  for (int c = 0; c < 16; c++)
    sum += psum[(b * 16 + c) * 16 + h] * __expf(pmax[(b * 16 + c) * 16 + h] - M);
  gmax[t] = M;
  ginv[t] = 1.f / (sum + 1e-9f);
}

// ---------- softmax stage 3: materialize attn in place ----------
__global__ void k_smax3(float* __restrict__ sc, const float* __restrict__ gmax,
                        const float* __restrict__ ginv) {
  const int r = blockIdx.x * 256 + threadIdx.x;
  const int b = r >> 13;
  float4 M[4], I[4];
#pragma unroll
  for (int k = 0; k < 4; k++) {
    M[k] = ((const float4*)(gmax + b * 16))[k];
    I[k] = ((const float4*)(ginv + b * 16))[k];
  }
  float4* row = (float4*)(sc + (size_t)r * 16);
#pragma unroll
  for (int k = 0; k < 4; k++) {
    float4 v = row[k];
    v.x = fminf(fmaxf(__expf(v.x - M[k].x) * I[k].x, 1e-9f), 1.f);
    v.y = fminf(fmaxf(__expf(v.y - M[k].y) * I[k].y, 1e-9f), 1.f);
    v.z = fminf(fmaxf(__expf(v.z - M[k].z) * I[k].z, 1e-9f), 1.f);
    v.w = fminf(fmaxf(__expf(v.w - M[k].w) * I[k].w, 1e-9f), 1.f);
    row[k] = v;
  }
}

// ---------- pass 2 over x: vn recompute + attn-weighted column accumulate ----------
__global__ __launch_bounds__(512) void k_accv(
    const float* __restrict__ x, const float* __restrict__ stats,
    const float* __restrict__ attn,
    const float* __restrict__ g1, const float* __restrict__ b1,
    const float* __restrict__ vg, const float* __restrict__ vb,
    float* __restrict__ part, int CH, int RPC) {
  const int b = blockIdx.x / CH, ch = blockIdx.x % CH;
  const int c0 = threadIdx.x * 2;
  const float2 gv = *(const float2*)(g1 + c0), bv = *(const float2*)(b1 + c0);
  const float2 vgv = *(const float2*)(vg + c0), vbv = *(const float2*)(vb + c0);
  float acc0[16], acc1[16];
#pragma unroll
  for (int h = 0; h < 16; h++) { acc0[h] = 0.f; acc1[h] = 0.f; }
  const int r0 = b * S + ch * RPC;
#pragma unroll 2
  for (int i = 0; i < RPC; i++) {
    const int r = r0 + i;
    const float4 st = ((const float4*)stats)[r];  // m1 rs1 m2 rs2
    const float2 xv = *(const float2*)(x + (size_t)r * D + c0);
    const float4* wr = (const float4*)(attn + (size_t)r * 16);
    const float4 w0 = wr[0], w1 = wr[1], w2 = wr[2], w3 = wr[3];
    float xn0 = (xv.x - st.x) * st.y * gv.x + bv.x;
    float xn1 = (xv.y - st.x) * st.y * gv.y + bv.y;
    const float v0 = (xn0 - st.z) * st.w * vgv.x + vbv.x;
    const float v1 = (xn1 - st.z) * st.w * vgv.y + vbv.y;
    acc0[0] = fmaf(w0.x, v0, acc0[0]);   acc1[0] = fmaf(w0.x, v1, acc1[0]);
    acc0[1] = fmaf(w0.y, v0, acc0[1]);   acc1[1] = fmaf(w0.y, v1, acc1[1]);
    acc0[2] = fmaf(w0.z, v0, acc0[2]);   acc1[2] = fmaf(w0.z, v1, acc1[2]);
    acc0[3] = fmaf(w0.w, v0, acc0[3]);   acc1[3] = fmaf(w0.w, v1, acc1[3]);
    acc0[4] = fmaf(w1.x, v0, acc0[4]);   acc1[4] = fmaf(w1.x, v1, acc1[4]);
    acc0[5] = fmaf(w1.y, v0, acc0[5]);   acc1[5] = fmaf(w1.y, v1, acc1[5]);
    acc0[6] = fmaf(w1.z, v0, acc0[6]);   acc1[6] = fmaf(w1.z, v1, acc1[6]);
    acc0[7] = fmaf(w1.w, v0, acc0[7]);   acc1[7] = fmaf(w1.w, v1, acc1[7]);
    acc0[8] = fmaf(w2.x, v0, acc0[8]);   acc1[8] = fmaf(w2.x, v1, acc1[8]);
    acc0[9] = fmaf(w2.y, v0, acc0[9]);   acc1[9] = fmaf(w2.y, v1, acc1[9]);
    acc0[10] = fmaf(w2.z, v0, acc0[10]); acc1[10] = fmaf(w2.z, v1, acc1[10]);
    acc0[11] = fmaf(w2.w, v0, acc0[11]); acc1[11] = fmaf(w2.w, v1, acc1[11]);
    acc0[12] = fmaf(w3.x, v0, acc0[12]); acc1[12] = fmaf(w3.x, v1, acc1[12]);
    acc0[13] = fmaf(w3.y, v0, acc0[13]); acc1[13] = fmaf(w3.y, v1, acc1[13]);
    acc0[14] = fmaf(w3.z, v0, acc0[14]); acc1[14] = fmaf(w3.z, v1, acc1[14]);
    acc0[15] = fmaf(w3.w, v0, acc0[15]); acc1[15] = fmaf(w3.w, v1, acc1[15]);
  }
  float* po = part + (size_t)blockIdx.x * (H * D);
#pragma unroll
  for (int h = 0; h < 16; h++)
    *(float2*)(po + h * D + c0) = make_float2(acc0[h], acc1[h]);
}

// ---------- reduce chunk partials -> wsum[b][h][d] ----------
__global__ void k_redpart(const float* __restrict__ part, float* __restrict__ wsum,
                          int CH) {
  const int b = blockIdx.x >> 4, h = blockIdx.x & 15;
  const int d = threadIdx.x * 4;
  float4 a = make_float4(0.f, 0.f, 0.f, 0.f);
  for (int k = 0; k < CH; k++) {
    const float4 p = *(const float4*)(part + ((size_t)(b * CH + k) * H + h) * D + d);
    a.x += p.x; a.y += p.y; a.z += p.z; a.w += p.w;
  }
  *(float4*)(wsum + ((size_t)b * H + h) * D + d) = a;
}

// ---------- out[b][j] = W[j,:] . src[b, (maybe head-sliced)] + bias[j] ----------
__global__ void k_proj8(const float* __restrict__ src, const float* __restrict__ W,
                        const float* __restrict__ bias, float* __restrict__ out,
                        int bstride, int hstride) {
  const int j = blockIdx.x, lane = threadIdx.x;
  const int h = j >> 6;
  const float4* wr = (const float4*)(W + (size_t)j * D);
  float acc[8];
#pragma unroll
  for (int b = 0; b < 8; b++) acc[b] = 0.f;
#pragma unroll
  for (int k = 0; k < 4; k++) {
    const float4 w4 = wr[lane + 64 * k];
#pragma unroll
    for (int b = 0; b < 8; b++) {
      const float4 s4 =
          ((const float4*)(src + (size_t)b * bstride + (size_t)h * hstride))[lane + 64 * k];
      acc[b] = fmaf(w4.x, s4.x, acc[b]); acc[b] = fmaf(w4.y, s4.y, acc[b]);
      acc[b] = fmaf(w4.z, s4.z, acc[b]); acc[b] = fmaf(w4.w, s4.w, acc[b]);
    }
  }
#pragma unroll
  for (int b = 0; b < 8; b++) acc[b] = wred_sum(acc[b]);
  if (!lane) {
    const float bj = bias[j];
#pragma unroll
    for (int b = 0; b < 8; b++) out[(size_t)b * D + j] = acc[b] + bj;
  }
}

extern "C" void kernel_launch(void* const* d_in, const int* in_sizes, int n_in,
                              void* d_out, int out_size, void* d_ws, size_t ws_size,
                              hipStream_t stream) {
  const float* x = (const float*)d_in[0];
  const float* query = (const float*)d_in[1];
  const float* norm_g = (const float*)d_in[2];
  const float* norm_b = (const float*)d_in[3];
  const float* nq_g = (const float*)d_in[4];
  const float* nq_b = (const float*)d_in[5];
  const float* nk_g = (const float*)d_in[6];
  const float* nk_b = (const float*)d_in[7];
  const float* nv_g = (const float*)d_in[8];
  const float* nv_b = (const float*)d_in[9];
  const float* no_g = (const float*)d_in[10];
  const float* no_b = (const float*)d_in[11];
  const float* Wq = (const float*)d_in[12];
  const float* bq = (const float*)d_in[13];
  const float* Wk = (const float*)d_in[14];
  // d_in[15] = bk: constant per (b,h) in scores -> cancels in softmax
  const float* Wv = (const float*)d_in[16];
  const float* bv = (const float*)d_in[17];
  const float* Wo = (const float*)d_in[18];
  const float* bo = (const float*)d_in[19];

  char* ws = (char*)d_ws;
  float* qn = (float*)(ws + 0);
  float* qv = (float*)(ws + 4096);
  float* Uf = (float*)(ws + 8192);
  h2* C1h = (h2*)(ws + 73728);
  h2* g1h = (h2*)(ws + 106496);
  h2* b1h = (h2*)(ws + 108544);
  float* hc = (float*)(ws + 110592);
  float* sconst = (float*)(ws + 110848);
  float* gmax = (float*)(ws + 110912);
  float* ginv = (float*)(ws + 111424);
  float* pmax = (float*)(ws + 111936);
  float* psum = (float*)(ws + 120128);
  float* stats = (float*)(ws + 128320);
  float* sc = (float*)(ws + 1176896);
  float* wsum = (float*)(ws + 5371200);
  float* av = (float*)(ws + 5895488);
  float* yb = (float*)(ws + 5928256);
  float* part = (float*)(ws + 5961024);

  int CH = 64;
  while (CH > 1 && 5961024ull + (size_t)B * CH * H * D * 4 > ws_size) CH >>= 1;
  const int RPC = S / CH;

  k_ln256<<<1, 256, 0, stream>>>(query, nq_g, nq_b, qn);
  k_qproj<<<256, 256, 0, stream>>>(qn, Wq, bq, qv);
  k_uproj<<<64, 256, 0, stream>>>(qv, Wk, Uf);
  k_prep0<<<1, 256, 0, stream>>>(norm_g, norm_b, g1h, b1h, sconst);
  k_prep1<<<16, 256, 0, stream>>>(Uf, norm_g, norm_b, nk_g, nk_b, C1h, hc);
  k_scores<<<1024, 256, 0, stream>>>(x, C1h, g1h, b1h, hc, sconst, stats, sc);
  k_smax1<<<128, 256, 0, stream>>>(sc, pmax, psum);
  k_smax2<<<1, 128, 0, stream>>>(pmax, psum, gmax, ginv);
  k_smax3<<<256, 256, 0, stream>>>(sc, gmax, ginv);
  k_accv<<<B * CH, 512, 0, stream>>>(x, stats, sc, norm_g, norm_b, nv_g, nv_b, part,
                                     CH, RPC);
  k_redpart<<<128, 256, 0, stream>>>(part, wsum, CH);
  k_proj8<<<1024, 64, 0, stream>>>(wsum, Wv, bv, av, H * D, D);  // V-proj on pooled
  k_proj8<<<1024, 64, 0, stream>>>(av, Wo, bo, yb, D, 0);        // O-proj
  k_ln256<<<8, 256, 0, stream>>>(yb, no_g, no_b, (float*)d_out);
}